// Round 1
// baseline (1364.239 us; speedup 1.0000x reference)
//
#include <hip/hip_runtime.h>
#include <math.h>

// Problem constants
#define BATCH   2
#define LSEQ    1024
#define DMODEL  1024
#define DI      2048      // D_INNER
#define NSTATE  16
#define DTR     64        // DT_RANK
#define SSMW    96        // DTR + 2*NSTATE
#define MROWS   2048      // BATCH*LSEQ

__device__ __forceinline__ float silu_f(float x) {
  return x / (1.f + __expf(-x));
}
__device__ __forceinline__ float softplus_f(float x) {
  // stable: max(x,0) + log1p(exp(-|x|))
  return fmaxf(x, 0.f) + log1pf(__expf(-fabsf(x)));
}

// ---------------------------------------------------------------------------
// Generic fp32 GEMM: C[M x N] = A[M x K] (row-major, lda) * B[K x N] (row-major, ldb)
// ACT==1: C = softplus(C + bias[col])
// Tile 128x128, BK=16, 256 threads, 8x8 microtile per thread.
// M must be a multiple of 128 and K a multiple of 16 (true for all uses here).
// N is bounds-checked (N=96 case).
// ---------------------------------------------------------------------------
template<int ACT>
__global__ __launch_bounds__(256) void gemm128(
    const float* __restrict__ A, int lda,
    const float* __restrict__ B, int ldb,
    const float* __restrict__ bias,
    float* __restrict__ C, int ldc,
    int N, int K)
{
  __shared__ __align__(16) float As[16][132];   // [k][m]
  __shared__ __align__(16) float Bs[16][132];   // [k][n]
  const int tid = threadIdx.x;
  const int bm = blockIdx.y * 128;
  const int bn = blockIdx.x * 128;
  const int tx = tid & 15;   // n
  const int ty = tid >> 4;   // m

  float acc[8][8];
#pragma unroll
  for (int i = 0; i < 8; ++i)
#pragma unroll
    for (int j = 0; j < 8; ++j) acc[i][j] = 0.f;

  const int ar = tid >> 1;        // 0..127 (row in A tile)
  const int ac = (tid & 1) * 8;   // 0 or 8 (k offset)
  const int br = tid >> 4;        // 0..15  (k row in B tile)
  const int bc = (tid & 15) * 8;  // 0..120 (col in B tile)

  for (int k0 = 0; k0 < K; k0 += 16) {
    // --- A tile: 128 rows x 16 k, store transposed As[k][m]
    {
      const float* ap = A + (size_t)(bm + ar) * lda + k0 + ac;
      float4 v0 = *(const float4*)(ap);
      float4 v1 = *(const float4*)(ap + 4);
      As[ac + 0][ar] = v0.x; As[ac + 1][ar] = v0.y;
      As[ac + 2][ar] = v0.z; As[ac + 3][ar] = v0.w;
      As[ac + 4][ar] = v1.x; As[ac + 5][ar] = v1.y;
      As[ac + 6][ar] = v1.z; As[ac + 7][ar] = v1.w;
    }
    // --- B tile: 16 k x 128 cols
    {
      const int col = bn + bc;
      const float* bp = B + (size_t)(k0 + br) * ldb + col;
      float4 v0, v1;
      if (col + 7 < N) {
        v0 = *(const float4*)(bp);
        v1 = *(const float4*)(bp + 4);
      } else {
        float tmp[8];
#pragma unroll
        for (int j = 0; j < 8; ++j) tmp[j] = (col + j < N) ? bp[j] : 0.f;
        v0 = make_float4(tmp[0], tmp[1], tmp[2], tmp[3]);
        v1 = make_float4(tmp[4], tmp[5], tmp[6], tmp[7]);
      }
      *(float4*)(&Bs[br][bc])     = v0;
      *(float4*)(&Bs[br][bc + 4]) = v1;
    }
    __syncthreads();

#pragma unroll
    for (int k = 0; k < 16; ++k) {
      float a[8], b[8];
      float4 t0 = *(const float4*)(&As[k][ty * 8]);
      float4 t1 = *(const float4*)(&As[k][ty * 8 + 4]);
      a[0] = t0.x; a[1] = t0.y; a[2] = t0.z; a[3] = t0.w;
      a[4] = t1.x; a[5] = t1.y; a[6] = t1.z; a[7] = t1.w;
      float4 u0 = *(const float4*)(&Bs[k][tx * 8]);
      float4 u1 = *(const float4*)(&Bs[k][tx * 8 + 4]);
      b[0] = u0.x; b[1] = u0.y; b[2] = u0.z; b[3] = u0.w;
      b[4] = u1.x; b[5] = u1.y; b[6] = u1.z; b[7] = u1.w;
#pragma unroll
      for (int i = 0; i < 8; ++i)
#pragma unroll
        for (int j = 0; j < 8; ++j)
          acc[i][j] = fmaf(a[i], b[j], acc[i][j]);
    }
    __syncthreads();
  }

  // epilogue
#pragma unroll
  for (int i = 0; i < 8; ++i) {
    const int row = bm + ty * 8 + i;
    float* cp = C + (size_t)row * ldc;
#pragma unroll
    for (int j = 0; j < 8; ++j) {
      const int col = bn + tx * 8 + j;
      if (col < N) {
        float v = acc[i][j];
        if (ACT == 1) v = softplus_f(v + bias[col]);
        cp[col] = v;
      }
    }
  }
}

// ---------------------------------------------------------------------------
// Depthwise causal conv (k=4) + bias + SiLU.  XV, XS: [B, L, DI]
// out[b,l,d] = silu( sum_k w[d,k]*xv[b,l-3+k,d] + cb[d] )
// ---------------------------------------------------------------------------
__global__ __launch_bounds__(256) void conv_silu_kernel(
    const float* __restrict__ XV, const float* __restrict__ cw,
    const float* __restrict__ cb, float* __restrict__ XS)
{
  const int idx = blockIdx.x * 256 + threadIdx.x;   // over B*L*DI
  const int d = idx & (DI - 1);
  const int bl = idx >> 11;      // b*L + l
  const int l = bl & (LSEQ - 1);
  const float w0 = cw[d * 4 + 0], w1 = cw[d * 4 + 1];
  const float w2 = cw[d * 4 + 2], w3 = cw[d * 4 + 3];
  const float* p = XV + (size_t)idx;
  float acc = cb[d];
  acc = fmaf(w3, p[0], acc);
  if (l >= 1) acc = fmaf(w2, p[-DI], acc);
  if (l >= 2) acc = fmaf(w1, p[-2 * DI], acc);
  if (l >= 3) acc = fmaf(w0, p[-3 * DI], acc);
  XS[idx] = silu_f(acc);
}

// ---------------------------------------------------------------------------
// Sequential selective scan. 16 lanes per (b,d) chain, lane = state n.
// h_l = exp(delta_l * A[d,n]) * h_{l-1} + delta_l * B_l[n] * xv_l
// y_l = sum_n h_l[n]*C_l[n] + xv_l * D[d]
// ---------------------------------------------------------------------------
__global__ __launch_bounds__(256) void scan_kernel(
    const float* __restrict__ DELTA, const float* __restrict__ XS,
    const float* __restrict__ SSMB, const float* __restrict__ A_log,
    const float* __restrict__ Dp, float* __restrict__ Y)
{
  const int t = blockIdx.x * 256 + threadIdx.x;
  const int n = t & 15;
  const int chain = t >> 4;          // 0..B*DI-1
  const int d = chain & (DI - 1);
  const int b = chain >> 11;
  const float A = -__expf(A_log[d * NSTATE + n]);
  const float Dd = Dp[d];
  float h = 0.f;
  const float* dp = DELTA + (size_t)b * LSEQ * DI + d;
  const float* xp = XS + (size_t)b * LSEQ * DI + d;
  const float* sp = SSMB + (size_t)b * LSEQ * SSMW;
  float* yp = Y + (size_t)b * LSEQ * DI + d;
  for (int l = 0; l < LSEQ; ++l) {
    const float delta = dp[(size_t)l * DI];
    const float xv = xp[(size_t)l * DI];
    const float Bv = sp[l * SSMW + DTR + n];
    const float Cv = sp[l * SSMW + DTR + NSTATE + n];
    const float dA = __expf(delta * A);
    h = fmaf(dA, h, delta * Bv * xv);
    float p = h * Cv;
    p += __shfl_xor(p, 1);
    p += __shfl_xor(p, 2);
    p += __shfl_xor(p, 4);
    p += __shfl_xor(p, 8);
    if (n == 0) yp[(size_t)l * DI] = fmaf(xv, Dd, p);
  }
}

// ---------------------------------------------------------------------------
extern "C" void kernel_launch(void* const* d_in, const int* in_sizes, int n_in,
                              void* d_out, int out_size, void* d_ws, size_t ws_size,
                              hipStream_t stream)
{
  const float* x      = (const float*)d_in[0];
  const float* W_in   = (const float*)d_in[1];
  const float* conv_w = (const float*)d_in[2];
  const float* conv_b = (const float*)d_in[3];
  const float* W_x    = (const float*)d_in[4];
  const float* W_dt   = (const float*)d_in[5];
  const float* b_dt   = (const float*)d_in[6];
  const float* A_log  = (const float*)d_in[7];
  const float* Dp     = (const float*)d_in[8];
  const float* W_out  = (const float*)d_in[9];
  float* out = (float*)d_out;
  float* ws  = (float*)d_ws;

  // workspace layout (floats)
  float* XV0   = ws;                          // B*L*DI = 4194304
  float* XS    = ws + 4194304;                // B*L*DI
  float* SSMB  = ws + 8388608;                // B*L*96 = 196608
  float* DELTA = ws + 8388608 + 196608;       // B*L*DI
  float* Y     = XV0;                         // reuse (XV0 dead after conv)

  dim3 blk(256);

  // 1) xv = x @ W_in      [2048x1024]*[1024x2048]
  gemm128<0><<<dim3(DI / 128, MROWS / 128), blk, 0, stream>>>(
      x, DMODEL, W_in, DI, nullptr, XV0, DI, DI, DMODEL);

  // 2) conv + silu
  conv_silu_kernel<<<dim3((BATCH * LSEQ * DI) / 256), blk, 0, stream>>>(
      XV0, conv_w, conv_b, XS);

  // 3) ssm = xs @ W_x     [2048x2048]*[2048x96]
  gemm128<0><<<dim3(1, MROWS / 128), blk, 0, stream>>>(
      XS, DI, W_x, SSMW, nullptr, SSMB, SSMW, SSMW, DI);

  // 4) delta = softplus(ssm[:, :64] @ W_dt + b_dt)   [2048x64]*[64x2048]
  gemm128<1><<<dim3(DI / 128, MROWS / 128), blk, 0, stream>>>(
      SSMB, SSMW, W_dt, DI, b_dt, DELTA, DI, DI, DTR);

  // 5) selective scan -> Y
  scan_kernel<<<dim3((BATCH * DI * NSTATE) / 256), blk, 0, stream>>>(
      DELTA, XS, SSMB, A_log, Dp, Y);

  // 6) out = y @ W_out    [2048x2048]*[2048x1024]
  gemm128<0><<<dim3(DMODEL / 128, MROWS / 128), blk, 0, stream>>>(
      Y, DI, W_out, DMODEL, nullptr, out, DMODEL, DMODEL, DI);
}

// Round 2
// 1012.568 us; speedup vs baseline: 1.3473x; 1.3473x over previous
//
#include <hip/hip_runtime.h>
#include <math.h>

// Problem constants
#define BATCH   2
#define LSEQ    1024
#define DMODEL  1024
#define DI      2048      // D_INNER
#define NSTATE  16
#define DTR     64        // DT_RANK
#define SSMW    96        // DTR + 2*NSTATE
#define MROWS   2048      // BATCH*LSEQ
#define CHUNK   128
#define NCHUNK  8         // LSEQ / CHUNK

__device__ __forceinline__ float silu_f(float x) {
  return x / (1.f + __expf(-x));
}
__device__ __forceinline__ float softplus_f(float x) {
  return fmaxf(x, 0.f) + log1pf(__expf(-fabsf(x)));
}

// ---------------------------------------------------------------------------
// Generic fp32 GEMM: C[M x N] = A[M x K] (row-major) * B[K x N] (row-major)
// ACT==1: C = softplus(C + bias[col]). Tile 128x128, BK=16, 8x8 microtile.
// ---------------------------------------------------------------------------
template<int ACT>
__global__ __launch_bounds__(256) void gemm128(
    const float* __restrict__ A, int lda,
    const float* __restrict__ B, int ldb,
    const float* __restrict__ bias,
    float* __restrict__ C, int ldc,
    int N, int K)
{
  __shared__ __align__(16) float As[16][132];   // [k][m]
  __shared__ __align__(16) float Bs[16][132];   // [k][n]
  const int tid = threadIdx.x;
  const int bm = blockIdx.y * 128;
  const int bn = blockIdx.x * 128;
  const int tx = tid & 15;   // n
  const int ty = tid >> 4;   // m

  float acc[8][8];
#pragma unroll
  for (int i = 0; i < 8; ++i)
#pragma unroll
    for (int j = 0; j < 8; ++j) acc[i][j] = 0.f;

  const int ar = tid >> 1;        // 0..127 (row in A tile)
  const int ac = (tid & 1) * 8;   // 0 or 8 (k offset)
  const int br = tid >> 4;        // 0..15  (k row in B tile)
  const int bc = (tid & 15) * 8;  // 0..120 (col in B tile)

  for (int k0 = 0; k0 < K; k0 += 16) {
    {
      const float* ap = A + (size_t)(bm + ar) * lda + k0 + ac;
      float4 v0 = *(const float4*)(ap);
      float4 v1 = *(const float4*)(ap + 4);
      As[ac + 0][ar] = v0.x; As[ac + 1][ar] = v0.y;
      As[ac + 2][ar] = v0.z; As[ac + 3][ar] = v0.w;
      As[ac + 4][ar] = v1.x; As[ac + 5][ar] = v1.y;
      As[ac + 6][ar] = v1.z; As[ac + 7][ar] = v1.w;
    }
    {
      const int col = bn + bc;
      const float* bp = B + (size_t)(k0 + br) * ldb + col;
      float4 v0, v1;
      if (col + 7 < N) {
        v0 = *(const float4*)(bp);
        v1 = *(const float4*)(bp + 4);
      } else {
        float tmp[8];
#pragma unroll
        for (int j = 0; j < 8; ++j) tmp[j] = (col + j < N) ? bp[j] : 0.f;
        v0 = make_float4(tmp[0], tmp[1], tmp[2], tmp[3]);
        v1 = make_float4(tmp[4], tmp[5], tmp[6], tmp[7]);
      }
      *(float4*)(&Bs[br][bc])     = v0;
      *(float4*)(&Bs[br][bc + 4]) = v1;
    }
    __syncthreads();

#pragma unroll
    for (int k = 0; k < 16; ++k) {
      float a[8], b[8];
      float4 t0 = *(const float4*)(&As[k][ty * 8]);
      float4 t1 = *(const float4*)(&As[k][ty * 8 + 4]);
      a[0] = t0.x; a[1] = t0.y; a[2] = t0.z; a[3] = t0.w;
      a[4] = t1.x; a[5] = t1.y; a[6] = t1.z; a[7] = t1.w;
      float4 u0 = *(const float4*)(&Bs[k][tx * 8]);
      float4 u1 = *(const float4*)(&Bs[k][tx * 8 + 4]);
      b[0] = u0.x; b[1] = u0.y; b[2] = u0.z; b[3] = u0.w;
      b[4] = u1.x; b[5] = u1.y; b[6] = u1.z; b[7] = u1.w;
#pragma unroll
      for (int i = 0; i < 8; ++i)
#pragma unroll
        for (int j = 0; j < 8; ++j)
          acc[i][j] = fmaf(a[i], b[j], acc[i][j]);
    }
    __syncthreads();
  }

#pragma unroll
  for (int i = 0; i < 8; ++i) {
    const int row = bm + ty * 8 + i;
    float* cp = C + (size_t)row * ldc;
#pragma unroll
    for (int j = 0; j < 8; ++j) {
      const int col = bn + tx * 8 + j;
      if (col < N) {
        float v = acc[i][j];
        if (ACT == 1) v = softplus_f(v + bias[col]);
        cp[col] = v;
      }
    }
  }
}

// ---------------------------------------------------------------------------
// Depthwise causal conv (k=4) + bias + SiLU.
// ---------------------------------------------------------------------------
__global__ __launch_bounds__(256) void conv_silu_kernel(
    const float* __restrict__ XV, const float* __restrict__ cw,
    const float* __restrict__ cb, float* __restrict__ XS)
{
  const int idx = blockIdx.x * 256 + threadIdx.x;   // over B*L*DI
  const int d = idx & (DI - 1);
  const int bl = idx >> 11;
  const int l = bl & (LSEQ - 1);
  const float w0 = cw[d * 4 + 0], w1 = cw[d * 4 + 1];
  const float w2 = cw[d * 4 + 2], w3 = cw[d * 4 + 3];
  const float* p = XV + (size_t)idx;
  float acc = cb[d];
  acc = fmaf(w3, p[0], acc);
  if (l >= 1) acc = fmaf(w2, p[-DI], acc);
  if (l >= 2) acc = fmaf(w1, p[-2 * DI], acc);
  if (l >= 3) acc = fmaf(w0, p[-3 * DI], acc);
  XS[idx] = silu_f(acc);
}

// ---------------------------------------------------------------------------
// Chunked parallel scan.
// idx layout: (((b*NCHUNK + c)*DI + d)*16 + n)  -- 16 consecutive lanes = n.
// Pass 1: per-chunk aggregates (aProd = prod dA, hPart = scan from h=0)
// Pass 2: prefix over chunks -> h_init per chunk
// Pass 3: re-scan chunk with h_init, emit y via 16-lane shuffle reduce.
// ---------------------------------------------------------------------------
__global__ __launch_bounds__(256) void scan_pass1(
    const float* __restrict__ DELTA, const float* __restrict__ XS,
    const float* __restrict__ SSMB, const float* __restrict__ A_log,
    float* __restrict__ AGG_A, float* __restrict__ AGG_H)
{
  const int idx = blockIdx.x * 256 + threadIdx.x;
  const int n = idx & 15;
  const int d = (idx >> 4) & (DI - 1);
  const int c = (idx >> 15) & (NCHUNK - 1);
  const int b = idx >> 18;
  const int l0 = c * CHUNK;

  const float A = -__expf(A_log[d * NSTATE + n]);
  const float* dp = DELTA + ((size_t)b * LSEQ + l0) * DI + d;
  const float* xp = XS + ((size_t)b * LSEQ + l0) * DI + d;
  const float* sp = SSMB + ((size_t)b * LSEQ + l0) * SSMW;

  float aProd = 1.f, h = 0.f;
  for (int l = 0; l < CHUNK; ++l) {
    const float delta = dp[(size_t)l * DI];
    const float xv = xp[(size_t)l * DI];
    const float Bv = sp[l * SSMW + DTR + n];
    const float dA = __expf(delta * A);
    aProd *= dA;
    h = fmaf(dA, h, delta * Bv * xv);
  }
  AGG_A[idx] = aProd;
  AGG_H[idx] = h;
}

__global__ __launch_bounds__(256) void scan_pass2(
    const float* __restrict__ AGG_A, const float* __restrict__ AGG_H,
    float* __restrict__ HINIT)
{
  const int t = blockIdx.x * 256 + threadIdx.x;   // over B*DI*NSTATE
  const int n = t & 15;
  const int d = (t >> 4) & (DI - 1);
  const int b = t >> 15;
  float h = 0.f;
#pragma unroll
  for (int c = 0; c < NCHUNK; ++c) {
    const size_t ai = ((((size_t)b * NCHUNK + c) * DI + d) << 4) + n;
    HINIT[ai] = h;
    h = fmaf(AGG_A[ai], h, AGG_H[ai]);
  }
}

__global__ __launch_bounds__(256) void scan_pass3(
    const float* __restrict__ DELTA, const float* __restrict__ XS,
    const float* __restrict__ SSMB, const float* __restrict__ A_log,
    const float* __restrict__ Dp, const float* __restrict__ HINIT,
    float* __restrict__ Y)
{
  const int idx = blockIdx.x * 256 + threadIdx.x;
  const int n = idx & 15;
  const int d = (idx >> 4) & (DI - 1);
  const int c = (idx >> 15) & (NCHUNK - 1);
  const int b = idx >> 18;
  const int l0 = c * CHUNK;

  const float A = -__expf(A_log[d * NSTATE + n]);
  const float Dd = Dp[d];
  const float* dp = DELTA + ((size_t)b * LSEQ + l0) * DI + d;
  const float* xp = XS + ((size_t)b * LSEQ + l0) * DI + d;
  const float* sp = SSMB + ((size_t)b * LSEQ + l0) * SSMW;
  float* yp = Y + ((size_t)b * LSEQ + l0) * DI + d;

  float h = HINIT[idx];
  for (int l = 0; l < CHUNK; ++l) {
    const float delta = dp[(size_t)l * DI];
    const float xv = xp[(size_t)l * DI];
    const float Bv = sp[l * SSMW + DTR + n];
    const float Cv = sp[l * SSMW + DTR + NSTATE + n];
    const float dA = __expf(delta * A);
    h = fmaf(dA, h, delta * Bv * xv);
    float p = h * Cv;
    p += __shfl_xor(p, 1);
    p += __shfl_xor(p, 2);
    p += __shfl_xor(p, 4);
    p += __shfl_xor(p, 8);
    if (n == 0) yp[(size_t)l * DI] = fmaf(xv, Dd, p);
  }
}

// ---------------------------------------------------------------------------
extern "C" void kernel_launch(void* const* d_in, const int* in_sizes, int n_in,
                              void* d_out, int out_size, void* d_ws, size_t ws_size,
                              hipStream_t stream)
{
  const float* x      = (const float*)d_in[0];
  const float* W_in   = (const float*)d_in[1];
  const float* conv_w = (const float*)d_in[2];
  const float* conv_b = (const float*)d_in[3];
  const float* W_x    = (const float*)d_in[4];
  const float* W_dt   = (const float*)d_in[5];
  const float* b_dt   = (const float*)d_in[6];
  const float* A_log  = (const float*)d_in[7];
  const float* Dp     = (const float*)d_in[8];
  const float* W_out  = (const float*)d_in[9];
  float* out = (float*)d_out;
  float* ws  = (float*)d_ws;

  // workspace layout (floats)
  const size_t NAGG = (size_t)BATCH * NCHUNK * DI * NSTATE;  // 524288
  float* XV0   = ws;                          // B*L*DI = 4194304
  float* XS    = ws + 4194304;                // B*L*DI
  float* SSMB  = ws + 8388608;                // B*L*96 = 196608
  float* DELTA = ws + 8388608 + 196608;       // B*L*DI
  float* HINIT = DELTA + 4194304;             // 524288
  // AGG arrays alias the (dead after conv) XV0 region; consumed in pass2,
  // before pass3 overwrites the region with Y.
  float* AGG_A = XV0;                         // 524288
  float* AGG_H = XV0 + NAGG;                  // 524288
  float* Y     = XV0;                         // written only in pass3

  dim3 blk(256);

  // 1) xv = x @ W_in
  gemm128<0><<<dim3(DI / 128, MROWS / 128), blk, 0, stream>>>(
      x, DMODEL, W_in, DI, nullptr, XV0, DI, DI, DMODEL);

  // 2) conv + silu
  conv_silu_kernel<<<dim3((BATCH * LSEQ * DI) / 256), blk, 0, stream>>>(
      XV0, conv_w, conv_b, XS);

  // 3) ssm = xs @ W_x
  gemm128<0><<<dim3(1, MROWS / 128), blk, 0, stream>>>(
      XS, DI, W_x, SSMW, nullptr, SSMB, SSMW, SSMW, DI);

  // 4) delta = softplus(ssm[:, :64] @ W_dt + b_dt)
  gemm128<1><<<dim3(DI / 128, MROWS / 128), blk, 0, stream>>>(
      SSMB, SSMW, W_dt, DI, b_dt, DELTA, DI, DI, DTR);

  // 5) chunked scan
  const int NTH = BATCH * NCHUNK * DI * NSTATE;      // 524288
  scan_pass1<<<dim3(NTH / 256), blk, 0, stream>>>(
      DELTA, XS, SSMB, A_log, AGG_A, AGG_H);
  scan_pass2<<<dim3((BATCH * DI * NSTATE) / 256), blk, 0, stream>>>(
      AGG_A, AGG_H, HINIT);
  scan_pass3<<<dim3(NTH / 256), blk, 0, stream>>>(
      DELTA, XS, SSMB, A_log, Dp, HINIT, Y);

  // 6) out = y @ W_out
  gemm128<0><<<dim3(DMODEL / 128, MROWS / 128), blk, 0, stream>>>(
      Y, DI, W_out, DMODEL, nullptr, out, DMODEL, DMODEL, DI);
}

// Round 3
// 336.770 us; speedup vs baseline: 4.0509x; 3.0067x over previous
//
#include <hip/hip_runtime.h>
#include <math.h>

// Problem constants
#define BATCH   2
#define LSEQ    1024
#define DMODEL  1024
#define DI      2048      // D_INNER
#define NSTATE  16
#define DTR     64        // DT_RANK
#define SSMP    128       // padded ssm width (96 -> 128); B at +64, C at +80
#define MROWS   2048      // BATCH*LSEQ
#define CHUNK   128
#define NCHUNK  8         // LSEQ / CHUNK

typedef unsigned short u16;
typedef __attribute__((ext_vector_type(8))) short short8;   // 8 bf16 (4 VGPRs)
typedef __attribute__((ext_vector_type(4))) float f32x4;

__device__ __forceinline__ float silu_f(float x) {
  return x / (1.f + __expf(-x));
}
__device__ __forceinline__ float softplus_f(float x) {
  return fmaxf(x, 0.f) + log1pf(__expf(-fabsf(x)));
}
__device__ __forceinline__ u16 f2bf(float f) {   // RNE
  unsigned u = __float_as_uint(f);
  return (u16)((u + 0x7fffu + ((u >> 16) & 1u)) >> 16);
}
__device__ __forceinline__ float bf2f(u16 v) {
  return __uint_as_float(((unsigned)v) << 16);
}

// ---------------------------------------------------------------------------
// fp32 -> bf16 elementwise convert (n multiple of 1024)
// ---------------------------------------------------------------------------
__global__ __launch_bounds__(256) void cvt_bf16(
    const float* __restrict__ in, u16* __restrict__ out)
{
  const int i = (blockIdx.x * 256 + threadIdx.x) * 4;
  float4 v = *(const float4*)(in + i);
  ushort4 o;
  o.x = f2bf(v.x); o.y = f2bf(v.y); o.z = f2bf(v.z); o.w = f2bf(v.w);
  *(ushort4*)(out + i) = o;
}

// ---------------------------------------------------------------------------
// fp32 [R][C] -> bf16 [C][R] tiled transpose. R,C multiples of 32.
// grid (C/32, R/32), block (32,8)
// ---------------------------------------------------------------------------
__global__ __launch_bounds__(256) void transpose_bf16(
    const float* __restrict__ in, u16* __restrict__ out, int R, int C)
{
  __shared__ float t[32][33];
  const int tx = threadIdx.x, ty = threadIdx.y;
  const int c0 = blockIdx.x * 32, r0 = blockIdx.y * 32;
#pragma unroll
  for (int k = 0; k < 4; ++k)
    t[ty + 8 * k][tx] = in[(size_t)(r0 + ty + 8 * k) * C + c0 + tx];
  __syncthreads();
#pragma unroll
  for (int k = 0; k < 4; ++k)
    out[(size_t)(c0 + ty + 8 * k) * R + r0 + tx] = f2bf(t[tx][ty + 8 * k]);
}

// ---------------------------------------------------------------------------
// bf16 MFMA GEMM: C[M x N] = A[M x K] * Bt[N x K]^T  (both bf16, K-contig)
// Tile 128x128, BK=32, 256 threads = 4 waves (2x2 of 64x64), 16 MFMA/wave/step.
// ACT==1: C = softplus(C + bias[col]).  SPLITK>1: atomicAdd partials (C pre-zeroed).
// Grid: (N/128, M/128, SPLITK). K multiple of 32*SPLITK.
// ---------------------------------------------------------------------------
template<int ACT, int SPLITK>
__global__ __launch_bounds__(256) void mgemm(
    const u16* __restrict__ A, int lda,
    const u16* __restrict__ Bt, int ldb,
    const float* __restrict__ bias,
    float* __restrict__ C, int ldc, int K)
{
  __shared__ u16 Al[128][40];   // padded: row stride 80B, balanced banks
  __shared__ u16 Bl[128][40];
  const int tid = threadIdx.x;
  const int bm = blockIdx.y * 128;
  const int bn = blockIdx.x * 128;
  const int lane = tid & 63;
  const int w = tid >> 6;
  const int wm = (w & 1) * 64;
  const int wn = (w >> 1) * 64;
  const int quad = lane >> 4;
  const int lm = lane & 15;

  const int Kper = K / SPLITK;
  const int k_beg = blockIdx.z * Kper;
  const int k_end = k_beg + Kper;

  f32x4 acc[4][4] = {};

  const int srow = tid >> 1;        // 0..127
  const int scol = (tid & 1) * 16;  // 0 or 16 elems (32B half-row)
  const u16* ap = A + (size_t)(bm + srow) * lda + scol;
  const u16* bp = Bt + (size_t)(bn + srow) * ldb + scol;

  for (int k0 = k_beg; k0 < k_end; k0 += 32) {
    uint4 va0 = *(const uint4*)(ap + k0);
    uint4 va1 = *(const uint4*)(ap + k0 + 8);
    uint4 vb0 = *(const uint4*)(bp + k0);
    uint4 vb1 = *(const uint4*)(bp + k0 + 8);
    *(uint4*)&Al[srow][scol]     = va0;
    *(uint4*)&Al[srow][scol + 8] = va1;
    *(uint4*)&Bl[srow][scol]     = vb0;
    *(uint4*)&Bl[srow][scol + 8] = vb1;
    __syncthreads();

    short8 a[4], b[4];
#pragma unroll
    for (int i = 0; i < 4; ++i)
      a[i] = *(const short8*)&Al[wm + i * 16 + lm][quad * 8];
#pragma unroll
    for (int j = 0; j < 4; ++j)
      b[j] = *(const short8*)&Bl[wn + j * 16 + lm][quad * 8];
#pragma unroll
    for (int i = 0; i < 4; ++i)
#pragma unroll
      for (int j = 0; j < 4; ++j)
        acc[i][j] = __builtin_amdgcn_mfma_f32_16x16x32_bf16(a[i], b[j], acc[i][j], 0, 0, 0);
    __syncthreads();
  }

#pragma unroll
  for (int i = 0; i < 4; ++i) {
#pragma unroll
    for (int r = 0; r < 4; ++r) {
      const int row = bm + wm + i * 16 + quad * 4 + r;
      float* cp = C + (size_t)row * ldc;
#pragma unroll
      for (int j = 0; j < 4; ++j) {
        const int col = bn + wn + j * 16 + lm;
        float v = acc[i][j][r];
        if (ACT == 1) v = softplus_f(v + bias[col]);
        if (SPLITK > 1) atomicAdd(&cp[col], v);
        else cp[col] = v;
      }
    }
  }
}

// ---------------------------------------------------------------------------
// Depthwise causal conv (k=4) + bias + SiLU. Reads XV fp32, writes XS bf16.
// ---------------------------------------------------------------------------
__global__ __launch_bounds__(256) void conv_silu_kernel(
    const float* __restrict__ XV, const float* __restrict__ cw,
    const float* __restrict__ cb, u16* __restrict__ XSb)
{
  const int idx = blockIdx.x * 256 + threadIdx.x;   // over B*L*DI
  const int d = idx & (DI - 1);
  const int bl = idx >> 11;
  const int l = bl & (LSEQ - 1);
  const float w0 = cw[d * 4 + 0], w1 = cw[d * 4 + 1];
  const float w2 = cw[d * 4 + 2], w3 = cw[d * 4 + 3];
  const float* p = XV + (size_t)idx;
  float acc = cb[d];
  acc = fmaf(w3, p[0], acc);
  if (l >= 1) acc = fmaf(w2, p[-DI], acc);
  if (l >= 2) acc = fmaf(w1, p[-2 * DI], acc);
  if (l >= 3) acc = fmaf(w0, p[-3 * DI], acc);
  XSb[idx] = f2bf(silu_f(acc));
}

// ---------------------------------------------------------------------------
// SSMB[:, 0:64] fp32 -> bf16 [2048][64] (for the delta GEMM A operand)
// ---------------------------------------------------------------------------
__global__ __launch_bounds__(256) void slice_dt_bf16(
    const float* __restrict__ SSMB, u16* __restrict__ SBdt)
{
  const int t = blockIdx.x * 256 + threadIdx.x;   // over 2048*64
  const int m = t >> 6;
  const int c = t & 63;
  SBdt[t] = f2bf(SSMB[m * SSMP + c]);
}

// ---------------------------------------------------------------------------
// Chunked parallel scan (idx = (((b*NCHUNK + c)*DI + d)*16 + n))
// ---------------------------------------------------------------------------
__global__ __launch_bounds__(256) void scan_pass1(
    const float* __restrict__ DELTA, const u16* __restrict__ XSb,
    const float* __restrict__ SSMB, const float* __restrict__ A_log,
    float* __restrict__ AGG_A, float* __restrict__ AGG_H)
{
  const int idx = blockIdx.x * 256 + threadIdx.x;
  const int n = idx & 15;
  const int d = (idx >> 4) & (DI - 1);
  const int c = (idx >> 15) & (NCHUNK - 1);
  const int b = idx >> 18;
  const int l0 = c * CHUNK;

  const float A = -__expf(A_log[d * NSTATE + n]);
  const float* dp = DELTA + ((size_t)b * LSEQ + l0) * DI + d;
  const u16*   xp = XSb + ((size_t)b * LSEQ + l0) * DI + d;
  const float* sp = SSMB + ((size_t)b * LSEQ + l0) * SSMP;

  float aProd = 1.f, h = 0.f;
  for (int l = 0; l < CHUNK; ++l) {
    const float delta = dp[(size_t)l * DI];
    const float xv = bf2f(xp[(size_t)l * DI]);
    const float Bv = sp[l * SSMP + DTR + n];
    const float dA = __expf(delta * A);
    aProd *= dA;
    h = fmaf(dA, h, delta * Bv * xv);
  }
  AGG_A[idx] = aProd;
  AGG_H[idx] = h;
}

__global__ __launch_bounds__(256) void scan_pass2(
    const float* __restrict__ AGG_A, const float* __restrict__ AGG_H,
    float* __restrict__ HINIT)
{
  const int t = blockIdx.x * 256 + threadIdx.x;   // over B*DI*NSTATE
  const int n = t & 15;
  const int d = (t >> 4) & (DI - 1);
  const int b = t >> 15;
  float h = 0.f;
#pragma unroll
  for (int c = 0; c < NCHUNK; ++c) {
    const size_t ai = ((((size_t)b * NCHUNK + c) * DI + d) << 4) + n;
    HINIT[ai] = h;
    h = fmaf(AGG_A[ai], h, AGG_H[ai]);
  }
}

__global__ __launch_bounds__(256) void scan_pass3(
    const float* __restrict__ DELTA, const u16* __restrict__ XSb,
    const float* __restrict__ SSMB, const float* __restrict__ A_log,
    const float* __restrict__ Dp, const float* __restrict__ HINIT,
    u16* __restrict__ Yb)
{
  const int idx = blockIdx.x * 256 + threadIdx.x;
  const int n = idx & 15;
  const int d = (idx >> 4) & (DI - 1);
  const int c = (idx >> 15) & (NCHUNK - 1);
  const int b = idx >> 18;
  const int l0 = c * CHUNK;

  const float A = -__expf(A_log[d * NSTATE + n]);
  const float Dd = Dp[d];
  const float* dp = DELTA + ((size_t)b * LSEQ + l0) * DI + d;
  const u16*   xp = XSb + ((size_t)b * LSEQ + l0) * DI + d;
  const float* sp = SSMB + ((size_t)b * LSEQ + l0) * SSMP;
  u16* yp = Yb + ((size_t)b * LSEQ + l0) * DI + d;

  float h = HINIT[idx];
  for (int l = 0; l < CHUNK; ++l) {
    const float delta = dp[(size_t)l * DI];
    const float xv = bf2f(xp[(size_t)l * DI]);
    const float Bv = sp[l * SSMP + DTR + n];
    const float Cv = sp[l * SSMP + DTR + NSTATE + n];
    const float dA = __expf(delta * A);
    h = fmaf(dA, h, delta * Bv * xv);
    float p = h * Cv;
    p += __shfl_xor(p, 1);
    p += __shfl_xor(p, 2);
    p += __shfl_xor(p, 4);
    p += __shfl_xor(p, 8);
    if (n == 0) yp[(size_t)l * DI] = f2bf(fmaf(xv, Dd, p));
  }
}

// ---------------------------------------------------------------------------
extern "C" void kernel_launch(void* const* d_in, const int* in_sizes, int n_in,
                              void* d_out, int out_size, void* d_ws, size_t ws_size,
                              hipStream_t stream)
{
  const float* x      = (const float*)d_in[0];
  const float* W_in   = (const float*)d_in[1];
  const float* conv_w = (const float*)d_in[2];
  const float* conv_b = (const float*)d_in[3];
  const float* W_x    = (const float*)d_in[4];
  const float* W_dt   = (const float*)d_in[5];
  const float* b_dt   = (const float*)d_in[6];
  const float* A_log  = (const float*)d_in[7];
  const float* Dp     = (const float*)d_in[8];
  const float* W_out  = (const float*)d_in[9];
  float* out = (float*)d_out;
  char* W = (char*)d_ws;

  const size_t MB = 1u << 20;
  // byte layout (total 46 MB):
  float* XV    = (float*)(W + 0);            // 16 MB  [2048][2048] fp32
  u16*   Yb    = (u16*)  (W + 0);            //  8 MB  (after conv; XV dead)
  float* AGG_A = (float*)(W + 8 * MB);       //  2 MB
  float* AGG_H = (float*)(W + 10 * MB);      //  2 MB
  float* HINIT = (float*)(W + 12 * MB);      //  2 MB
  float* DELTA = (float*)(W + 16 * MB);      // 16 MB  [2048][2048] fp32
  u16*   x_bf  = (u16*)  (W + 16 * MB);      //  4 MB  (early; dead before gemm4)
  u16*   WinT  = (u16*)  (W + 20 * MB);      //  4 MB  (early; dead before gemm4)
  u16*   XSb   = (u16*)  (W + 32 * MB);      //  8 MB  [2048][2048] bf16
  float* SSMB  = (float*)(W + 40 * MB);      //  1 MB  [2048][128] fp32
  u16*   WoutT = (u16*)  (W + 41 * MB);      //  4 MB  [1024][2048] bf16
  u16*   WxT   = (u16*)  (W + 45 * MB);      // .5 MB  [128][2048] bf16 (pad zeroed)
  u16*   WdtT  = (u16*)  (W + 45 * MB + 512 * 1024);  // .25 MB [2048][64]
  u16*   SBdt  = (u16*)  (W + 45 * MB + 768 * 1024);  // .25 MB [2048][64]

  dim3 blk(256);
  dim3 tblk(32, 8);

  // 0) input converts / weight transposes (all bf16, K-contiguous)
  cvt_bf16<<<dim3(2048), blk, 0, stream>>>(x, x_bf);                         // 2M elems
  transpose_bf16<<<dim3(64, 32), tblk, 0, stream>>>(W_in, WinT, 1024, 2048); // ->[2048][1024]
  hipMemsetAsync(WxT, 0, 128 * 2048 * sizeof(u16), stream);
  transpose_bf16<<<dim3(3, 64), tblk, 0, stream>>>(W_x, WxT, 2048, 96);      // ->[96][2048] in [128][2048]
  transpose_bf16<<<dim3(64, 2), tblk, 0, stream>>>(W_dt, WdtT, 64, 2048);    // ->[2048][64]
  transpose_bf16<<<dim3(32, 64), tblk, 0, stream>>>(W_out, WoutT, 2048, 1024); // ->[1024][2048]

  // 1) xv = x @ W_in   (M=2048 N=2048 K=1024) -> XV fp32
  mgemm<0, 1><<<dim3(16, 16, 1), blk, 0, stream>>>(
      x_bf, DMODEL, WinT, DMODEL, nullptr, XV, DI, DMODEL);

  // 2) conv + silu -> XSb bf16
  conv_silu_kernel<<<dim3((BATCH * LSEQ * DI) / 256), blk, 0, stream>>>(
      XV, conv_w, conv_b, XSb);

  // 3) ssm = xs @ W_x  (M=2048 N=128pad K=2048, split-K=8) -> SSMB fp32
  hipMemsetAsync(SSMB, 0, MROWS * SSMP * sizeof(float), stream);
  mgemm<0, 8><<<dim3(1, 16, 8), blk, 0, stream>>>(
      XSb, DI, WxT, DI, nullptr, SSMB, SSMP, DI);

  // 4) delta = softplus(ssm[:, :64] @ W_dt + b_dt)  (K=64) -> DELTA fp32
  slice_dt_bf16<<<dim3(512), blk, 0, stream>>>(SSMB, SBdt);
  mgemm<1, 1><<<dim3(16, 16, 1), blk, 0, stream>>>(
      SBdt, DTR, WdtT, DTR, b_dt, DELTA, DI, DTR);

  // 5) chunked scan -> Yb bf16
  const int NTH = BATCH * NCHUNK * DI * NSTATE;      // 524288
  scan_pass1<<<dim3(NTH / 256), blk, 0, stream>>>(
      DELTA, XSb, SSMB, A_log, AGG_A, AGG_H);
  scan_pass2<<<dim3((BATCH * DI * NSTATE) / 256), blk, 0, stream>>>(
      AGG_A, AGG_H, HINIT);
  scan_pass3<<<dim3(NTH / 256), blk, 0, stream>>>(
      DELTA, XSb, SSMB, A_log, Dp, HINIT, Yb);

  // 6) out = y @ W_out  (M=2048 N=1024 K=2048) -> d_out fp32
  mgemm<0, 1><<<dim3(8, 16, 1), blk, 0, stream>>>(
      Yb, DI, WoutT, DI, nullptr, out, DMODEL, DI);
}

// Round 4
// 290.570 us; speedup vs baseline: 4.6951x; 1.1590x over previous
//
#include <hip/hip_runtime.h>
#include <math.h>

// Problem constants
#define BATCH   2
#define LSEQ    1024
#define DMODEL  1024
#define DI      2048      // D_INNER
#define NSTATE  16
#define DTR     64        // DT_RANK
#define SSMP    128       // padded ssm width (96 -> 128); B at +64, C at +80
#define MROWS   2048      // BATCH*LSEQ
#define CHUNK   32
#define NCHUNK  32        // LSEQ / CHUNK

typedef unsigned short u16;
typedef __attribute__((ext_vector_type(8))) short short8;   // 8 bf16 (4 VGPRs)
typedef __attribute__((ext_vector_type(4))) float f32x4;

__device__ __forceinline__ float silu_f(float x) {
  return x / (1.f + __expf(-x));
}
__device__ __forceinline__ float softplus_f(float x) {
  return fmaxf(x, 0.f) + log1pf(__expf(-fabsf(x)));
}
__device__ __forceinline__ u16 f2bf(float f) {   // RNE
  unsigned u = __float_as_uint(f);
  return (u16)((u + 0x7fffu + ((u >> 16) & 1u)) >> 16);
}
__device__ __forceinline__ float bf2f(u16 v) {
  return __uint_as_float(((unsigned)v) << 16);
}

// ---------------------------------------------------------------------------
// fp32 -> bf16 elementwise convert (n multiple of 1024)
// ---------------------------------------------------------------------------
__global__ __launch_bounds__(256) void cvt_bf16(
    const float* __restrict__ in, u16* __restrict__ out)
{
  const int i = (blockIdx.x * 256 + threadIdx.x) * 4;
  float4 v = *(const float4*)(in + i);
  ushort4 o;
  o.x = f2bf(v.x); o.y = f2bf(v.y); o.z = f2bf(v.z); o.w = f2bf(v.w);
  *(ushort4*)(out + i) = o;
}

// ---------------------------------------------------------------------------
// fp32 [R][C] -> bf16 [C][R] tiled transpose. R,C multiples of 32.
// ---------------------------------------------------------------------------
__global__ __launch_bounds__(256) void transpose_bf16(
    const float* __restrict__ in, u16* __restrict__ out, int R, int C)
{
  __shared__ float t[32][33];
  const int tx = threadIdx.x, ty = threadIdx.y;
  const int c0 = blockIdx.x * 32, r0 = blockIdx.y * 32;
#pragma unroll
  for (int k = 0; k < 4; ++k)
    t[ty + 8 * k][tx] = in[(size_t)(r0 + ty + 8 * k) * C + c0 + tx];
  __syncthreads();
#pragma unroll
  for (int k = 0; k < 4; ++k)
    out[(size_t)(c0 + ty + 8 * k) * R + r0 + tx] = f2bf(t[tx][ty + 8 * k]);
}

// ---------------------------------------------------------------------------
// bf16 MFMA GEMM: C[M x N] = A[M x K] * Bt[N x K]^T  (both bf16, K-contig)
// Tile 128x128, BK=32, 256 threads = 4 waves (2x2 of 64x64).
// ---------------------------------------------------------------------------
template<int ACT, int SPLITK>
__global__ __launch_bounds__(256) void mgemm(
    const u16* __restrict__ A, int lda,
    const u16* __restrict__ Bt, int ldb,
    const float* __restrict__ bias,
    float* __restrict__ C, int ldc, int K)
{
  __shared__ u16 Al[128][40];   // padded: row stride 80B, balanced banks
  __shared__ u16 Bl[128][40];
  const int tid = threadIdx.x;
  const int bm = blockIdx.y * 128;
  const int bn = blockIdx.x * 128;
  const int lane = tid & 63;
  const int w = tid >> 6;
  const int wm = (w & 1) * 64;
  const int wn = (w >> 1) * 64;
  const int quad = lane >> 4;
  const int lm = lane & 15;

  const int Kper = K / SPLITK;
  const int k_beg = blockIdx.z * Kper;
  const int k_end = k_beg + Kper;

  f32x4 acc[4][4] = {};

  const int srow = tid >> 1;        // 0..127
  const int scol = (tid & 1) * 16;  // 0 or 16 elems (32B half-row)
  const u16* ap = A + (size_t)(bm + srow) * lda + scol;
  const u16* bp = Bt + (size_t)(bn + srow) * ldb + scol;

  for (int k0 = k_beg; k0 < k_end; k0 += 32) {
    uint4 va0 = *(const uint4*)(ap + k0);
    uint4 va1 = *(const uint4*)(ap + k0 + 8);
    uint4 vb0 = *(const uint4*)(bp + k0);
    uint4 vb1 = *(const uint4*)(bp + k0 + 8);
    *(uint4*)&Al[srow][scol]     = va0;
    *(uint4*)&Al[srow][scol + 8] = va1;
    *(uint4*)&Bl[srow][scol]     = vb0;
    *(uint4*)&Bl[srow][scol + 8] = vb1;
    __syncthreads();

    short8 a[4], b[4];
#pragma unroll
    for (int i = 0; i < 4; ++i)
      a[i] = *(const short8*)&Al[wm + i * 16 + lm][quad * 8];
#pragma unroll
    for (int j = 0; j < 4; ++j)
      b[j] = *(const short8*)&Bl[wn + j * 16 + lm][quad * 8];
#pragma unroll
    for (int i = 0; i < 4; ++i)
#pragma unroll
      for (int j = 0; j < 4; ++j)
        acc[i][j] = __builtin_amdgcn_mfma_f32_16x16x32_bf16(a[i], b[j], acc[i][j], 0, 0, 0);
    __syncthreads();
  }

#pragma unroll
  for (int i = 0; i < 4; ++i) {
#pragma unroll
    for (int r = 0; r < 4; ++r) {
      const int row = bm + wm + i * 16 + quad * 4 + r;
      float* cp = C + (size_t)row * ldc;
#pragma unroll
      for (int j = 0; j < 4; ++j) {
        const int col = bn + wn + j * 16 + lm;
        float v = acc[i][j][r];
        if (ACT == 1) v = softplus_f(v + bias[col]);
        if (SPLITK > 1) atomicAdd(&cp[col], v);
        else cp[col] = v;
      }
    }
  }
}

// ---------------------------------------------------------------------------
// Depthwise causal conv (k=4) + bias + SiLU. Reads XV fp32, writes XS bf16.
// ---------------------------------------------------------------------------
__global__ __launch_bounds__(256) void conv_silu_kernel(
    const float* __restrict__ XV, const float* __restrict__ cw,
    const float* __restrict__ cb, u16* __restrict__ XSb)
{
  const int idx = blockIdx.x * 256 + threadIdx.x;   // over B*L*DI
  const int d = idx & (DI - 1);
  const int bl = idx >> 11;
  const int l = bl & (LSEQ - 1);
  const float w0 = cw[d * 4 + 0], w1 = cw[d * 4 + 1];
  const float w2 = cw[d * 4 + 2], w3 = cw[d * 4 + 3];
  const float* p = XV + (size_t)idx;
  float acc = cb[d];
  acc = fmaf(w3, p[0], acc);
  if (l >= 1) acc = fmaf(w2, p[-DI], acc);
  if (l >= 2) acc = fmaf(w1, p[-2 * DI], acc);
  if (l >= 3) acc = fmaf(w0, p[-3 * DI], acc);
  XSb[idx] = f2bf(silu_f(acc));
}

// ---------------------------------------------------------------------------
// SSMB[:, 0:64] fp32 -> bf16 [2048][64]
// ---------------------------------------------------------------------------
__global__ __launch_bounds__(256) void slice_dt_bf16(
    const float* __restrict__ SSMB, u16* __restrict__ SBdt)
{
  const int t = blockIdx.x * 256 + threadIdx.x;   // over 2048*64
  const int m = t >> 6;
  const int c = t & 63;
  SBdt[t] = f2bf(SSMB[m * SSMP + c]);
}

// ---------------------------------------------------------------------------
// Chunked parallel scan, register-state version.
// One thread per (b, chunk, d) holding all 16 states in registers.
// Block = 256 consecutive d; grid = B*NCHUNK*(DI/256) = 512.
// Aggregate layout: agg[((b*NCHUNK + c)*DI + d)*16 + n].
// ---------------------------------------------------------------------------
__global__ __launch_bounds__(256) void scan_pass1(
    const float* __restrict__ DELTA, const u16* __restrict__ XSb,
    const float* __restrict__ SSMB, const float* __restrict__ A_log,
    float* __restrict__ AGG_A, float* __restrict__ AGG_H)
{
  __shared__ float Bs[CHUNK * 16];
  const int tid = threadIdx.x;
  const int db = blockIdx.x & 7;
  const int c  = (blockIdx.x >> 3) & (NCHUNK - 1);
  const int b  = blockIdx.x >> 8;
  const int d  = db * 256 + tid;
  const int l0 = c * CHUNK;

  for (int i = tid; i < CHUNK * 16; i += 256) {
    const int l = i >> 4, n = i & 15;
    Bs[i] = SSMB[((size_t)(b * LSEQ + l0 + l)) * SSMP + DTR + n];
  }
  __syncthreads();

  float An[16];
  {
    const float* ar = A_log + d * 16;
#pragma unroll
    for (int n = 0; n < 16; ++n) An[n] = -__expf(ar[n]);
  }

  float h[16];
#pragma unroll
  for (int n = 0; n < 16; ++n) h[n] = 0.f;
  float S = 0.f;

  const float* dp = DELTA + ((size_t)(b * LSEQ + l0)) * DI + d;
  const u16*   xp = XSb   + ((size_t)(b * LSEQ + l0)) * DI + d;

  for (int l = 0; l < CHUNK; ++l) {
    const float delta = *dp; dp += DI;
    const float xv = bf2f(*xp); xp += DI;
    S += delta;
    const float dt = delta * xv;
    const f32x4 b0 = *(const f32x4*)&Bs[l * 16];
    const f32x4 b1 = *(const f32x4*)&Bs[l * 16 + 4];
    const f32x4 b2 = *(const f32x4*)&Bs[l * 16 + 8];
    const f32x4 b3 = *(const f32x4*)&Bs[l * 16 + 12];
#pragma unroll
    for (int n = 0; n < 16; ++n) {
      const float Bv = (n < 4) ? b0[n & 3] : (n < 8) ? b1[n & 3] : (n < 12) ? b2[n & 3] : b3[n & 3];
      const float dA = __expf(delta * An[n]);
      h[n] = fmaf(dA, h[n], Bv * dt);
    }
  }

  const size_t base = (((size_t)(b * NCHUNK + c) * DI + d) << 4);
  f32x4 oa[4], oh[4];
#pragma unroll
  for (int q = 0; q < 4; ++q) {
#pragma unroll
    for (int r = 0; r < 4; ++r) {
      oa[q][r] = __expf(An[q * 4 + r] * S);
      oh[q][r] = h[q * 4 + r];
    }
    *(f32x4*)&AGG_A[base + q * 4] = oa[q];
    *(f32x4*)&AGG_H[base + q * 4] = oh[q];
  }
}

// In-place prefix over chunks: AGG_H[ai] is REPLACED by h_init (the exclusive
// prefix), consuming AGG_A.
__global__ __launch_bounds__(256) void scan_pass2(
    const float* __restrict__ AGG_A, float* __restrict__ AGG_H)
{
  const int t = blockIdx.x * 256 + threadIdx.x;   // over B*DI*NSTATE
  const int dn = t & (DI * NSTATE - 1);
  const int b = t >> 15;
  size_t ai = (size_t)b * NCHUNK * DI * NSTATE + dn;
  const size_t stride = (size_t)DI * NSTATE;
  float h = 0.f;
#pragma unroll
  for (int c = 0; c < NCHUNK; ++c) {
    const float a = AGG_A[ai];
    const float hp = AGG_H[ai];
    AGG_H[ai] = h;
    h = fmaf(a, h, hp);
    ai += stride;
  }
}

__global__ __launch_bounds__(256) void scan_pass3(
    const float* __restrict__ DELTA, const u16* __restrict__ XSb,
    const float* __restrict__ SSMB, const float* __restrict__ A_log,
    const float* __restrict__ Dp, const float* __restrict__ HINIT,
    u16* __restrict__ Yb)
{
  __shared__ float Bs[CHUNK * 16];
  __shared__ float Cs[CHUNK * 16];
  const int tid = threadIdx.x;
  const int db = blockIdx.x & 7;
  const int c  = (blockIdx.x >> 3) & (NCHUNK - 1);
  const int b  = blockIdx.x >> 8;
  const int d  = db * 256 + tid;
  const int l0 = c * CHUNK;

  for (int i = tid; i < CHUNK * 16; i += 256) {
    const int l = i >> 4, n = i & 15;
    const size_t row = ((size_t)(b * LSEQ + l0 + l)) * SSMP;
    Bs[i] = SSMB[row + DTR + n];
    Cs[i] = SSMB[row + DTR + NSTATE + n];
  }
  __syncthreads();

  float An[16];
  {
    const float* ar = A_log + d * 16;
#pragma unroll
    for (int n = 0; n < 16; ++n) An[n] = -__expf(ar[n]);
  }
  const float Dd = Dp[d];

  const size_t base = (((size_t)(b * NCHUNK + c) * DI + d) << 4);
  float h[16];
#pragma unroll
  for (int q = 0; q < 4; ++q) {
    const f32x4 hv = *(const f32x4*)&HINIT[base + q * 4];
#pragma unroll
    for (int r = 0; r < 4; ++r) h[q * 4 + r] = hv[r];
  }

  const float* dp = DELTA + ((size_t)(b * LSEQ + l0)) * DI + d;
  const u16*   xp = XSb   + ((size_t)(b * LSEQ + l0)) * DI + d;
  u16*         yp = Yb    + ((size_t)(b * LSEQ + l0)) * DI + d;

  for (int l = 0; l < CHUNK; ++l) {
    const float delta = *dp; dp += DI;
    const float xv = bf2f(*xp); xp += DI;
    const float dt = delta * xv;
    float y = xv * Dd;
    const f32x4 b0 = *(const f32x4*)&Bs[l * 16];
    const f32x4 b1 = *(const f32x4*)&Bs[l * 16 + 4];
    const f32x4 b2 = *(const f32x4*)&Bs[l * 16 + 8];
    const f32x4 b3 = *(const f32x4*)&Bs[l * 16 + 12];
    const f32x4 c0 = *(const f32x4*)&Cs[l * 16];
    const f32x4 c1 = *(const f32x4*)&Cs[l * 16 + 4];
    const f32x4 c2 = *(const f32x4*)&Cs[l * 16 + 8];
    const f32x4 c3 = *(const f32x4*)&Cs[l * 16 + 12];
#pragma unroll
    for (int n = 0; n < 16; ++n) {
      const float Bv = (n < 4) ? b0[n & 3] : (n < 8) ? b1[n & 3] : (n < 12) ? b2[n & 3] : b3[n & 3];
      const float Cv = (n < 4) ? c0[n & 3] : (n < 8) ? c1[n & 3] : (n < 12) ? c2[n & 3] : c3[n & 3];
      const float dA = __expf(delta * An[n]);
      h[n] = fmaf(dA, h[n], Bv * dt);
      y = fmaf(h[n], Cv, y);
    }
    *yp = f2bf(y); yp += DI;
  }
}

// ---------------------------------------------------------------------------
extern "C" void kernel_launch(void* const* d_in, const int* in_sizes, int n_in,
                              void* d_out, int out_size, void* d_ws, size_t ws_size,
                              hipStream_t stream)
{
  const float* x      = (const float*)d_in[0];
  const float* W_in   = (const float*)d_in[1];
  const float* conv_w = (const float*)d_in[2];
  const float* conv_b = (const float*)d_in[3];
  const float* W_x    = (const float*)d_in[4];
  const float* W_dt   = (const float*)d_in[5];
  const float* b_dt   = (const float*)d_in[6];
  const float* A_log  = (const float*)d_in[7];
  const float* Dp     = (const float*)d_in[8];
  const float* W_out  = (const float*)d_in[9];
  float* out = (float*)d_out;
  char* W = (char*)d_ws;

  const size_t MB = 1u << 20;
  // byte layout (46 MB total), time-multiplexed:
  // [0,16)   : XV fp32 (steps 1-2) -> AGG_A [0,8) + AGG_H [8,16) (steps 5) -> Yb [0,8) (step 5c+)
  // [16,32)  : x_bf [16,20) + WinT [20,24) (step 0-1) -> DELTA (steps 4-5)
  // [32,40)  : XSb bf16
  // [40,41)  : SSMB fp32 [2048][128]
  // [41,45)  : WoutT
  // [45,46)  : WxT [45,45.5) + WdtT [45.5,45.75) + SBdt [45.75,46)
  float* XV    = (float*)(W + 0);
  float* AGG_A = (float*)(W + 0);
  float* AGG_H = (float*)(W + 8 * MB);
  u16*   Yb    = (u16*)  (W + 0);
  u16*   x_bf  = (u16*)  (W + 16 * MB);
  u16*   WinT  = (u16*)  (W + 20 * MB);
  float* DELTA = (float*)(W + 16 * MB);
  u16*   XSb   = (u16*)  (W + 32 * MB);
  float* SSMB  = (float*)(W + 40 * MB);
  u16*   WoutT = (u16*)  (W + 41 * MB);
  u16*   WxT   = (u16*)  (W + 45 * MB);
  u16*   WdtT  = (u16*)  (W + 45 * MB + 512 * 1024);
  u16*   SBdt  = (u16*)  (W + 45 * MB + 768 * 1024);

  dim3 blk(256);
  dim3 tblk(32, 8);

  // 0) input converts / weight transposes (all bf16, K-contiguous)
  cvt_bf16<<<dim3(2048), blk, 0, stream>>>(x, x_bf);
  transpose_bf16<<<dim3(64, 32), tblk, 0, stream>>>(W_in, WinT, 1024, 2048);
  hipMemsetAsync(WxT, 0, 128 * 2048 * sizeof(u16), stream);
  transpose_bf16<<<dim3(3, 64), tblk, 0, stream>>>(W_x, WxT, 2048, 96);
  transpose_bf16<<<dim3(64, 2), tblk, 0, stream>>>(W_dt, WdtT, 64, 2048);
  transpose_bf16<<<dim3(32, 64), tblk, 0, stream>>>(W_out, WoutT, 2048, 1024);

  // 1) xv = x @ W_in   (M=2048 N=2048 K=1024) -> XV fp32
  mgemm<0, 1><<<dim3(16, 16, 1), blk, 0, stream>>>(
      x_bf, DMODEL, WinT, DMODEL, nullptr, XV, DI, DMODEL);

  // 2) conv + silu -> XSb bf16
  conv_silu_kernel<<<dim3((BATCH * LSEQ * DI) / 256), blk, 0, stream>>>(
      XV, conv_w, conv_b, XSb);

  // 3) ssm = xs @ W_x  (M=2048 N=128pad K=2048, split-K=8) -> SSMB fp32
  hipMemsetAsync(SSMB, 0, MROWS * SSMP * sizeof(float), stream);
  mgemm<0, 8><<<dim3(1, 16, 8), blk, 0, stream>>>(
      XSb, DI, WxT, DI, nullptr, SSMB, SSMP, DI);

  // 4) delta = softplus(ssm[:, :64] @ W_dt + b_dt)  (K=64) -> DELTA fp32
  slice_dt_bf16<<<dim3(512), blk, 0, stream>>>(SSMB, SBdt);
  mgemm<1, 1><<<dim3(16, 16, 1), blk, 0, stream>>>(
      SBdt, DTR, WdtT, DTR, b_dt, DELTA, DI, DTR);

  // 5) chunked scan (register-state): pass1 -> pass2 (in-place HINIT) -> pass3
  scan_pass1<<<dim3(BATCH * NCHUNK * (DI / 256)), blk, 0, stream>>>(
      DELTA, XSb, SSMB, A_log, AGG_A, AGG_H);
  scan_pass2<<<dim3((BATCH * DI * NSTATE) / 256), blk, 0, stream>>>(
      AGG_A, AGG_H);
  scan_pass3<<<dim3(BATCH * NCHUNK * (DI / 256)), blk, 0, stream>>>(
      DELTA, XSb, SSMB, A_log, Dp, AGG_H, Yb);

  // 6) out = y @ W_out  (M=2048 N=1024 K=2048) -> d_out fp32
  mgemm<0, 1><<<dim3(8, 16, 1), blk, 0, stream>>>(
      Yb, DI, WoutT, DI, nullptr, out, DMODEL, DI);
}

// Round 5
// 264.039 us; speedup vs baseline: 5.1668x; 1.1005x over previous
//
#include <hip/hip_runtime.h>
#include <math.h>

// Problem constants
#define BATCH   2
#define LSEQ    1024
#define DMODEL  1024
#define DI      2048      // D_INNER
#define NSTATE  16
#define DTR     64        // DT_RANK
#define SSMP    128       // padded ssm width (96 -> 128); B at +64, C at +80
#define MROWS   2048      // BATCH*LSEQ
#define CHUNK   32
#define NCHUNK  32        // LSEQ / CHUNK

typedef unsigned short u16;
typedef __attribute__((ext_vector_type(8))) short short8;   // 8 bf16 (4 VGPRs)
typedef __attribute__((ext_vector_type(4))) float f32x4;

__device__ __forceinline__ float silu_f(float x) {
  return x / (1.f + __expf(-x));
}
__device__ __forceinline__ float softplus_f(float x) {
  return fmaxf(x, 0.f) + log1pf(__expf(-fabsf(x)));
}
__device__ __forceinline__ u16 f2bf(float f) {   // RNE
  unsigned u = __float_as_uint(f);
  return (u16)((u + 0x7fffu + ((u >> 16) & 1u)) >> 16);
}
__device__ __forceinline__ float bf2f(u16 v) {
  return __uint_as_float(((unsigned)v) << 16);
}

// async global -> LDS, 16 B per lane; LDS dest = wave-uniform base + lane*16
__device__ __forceinline__ void gload_lds16(const u16* g, u16* l) {
  __builtin_amdgcn_global_load_lds(
      (const __attribute__((address_space(1))) unsigned int*)(const void*)g,
      (__attribute__((address_space(3))) unsigned int*)(void*)l, 16, 0, 0);
}

// ---------------------------------------------------------------------------
// fp32 -> bf16 elementwise convert
// ---------------------------------------------------------------------------
__global__ __launch_bounds__(256) void cvt_bf16(
    const float* __restrict__ in, u16* __restrict__ out)
{
  const int i = (blockIdx.x * 256 + threadIdx.x) * 4;
  float4 v = *(const float4*)(in + i);
  ushort4 o;
  o.x = f2bf(v.x); o.y = f2bf(v.y); o.z = f2bf(v.z); o.w = f2bf(v.w);
  *(ushort4*)(out + i) = o;
}

// ---------------------------------------------------------------------------
// fp32 [R][C] -> bf16 [C][R] tiled transpose. R,C multiples of 32.
// ---------------------------------------------------------------------------
__global__ __launch_bounds__(256) void transpose_bf16(
    const float* __restrict__ in, u16* __restrict__ out, int R, int C)
{
  __shared__ float t[32][33];
  const int tx = threadIdx.x, ty = threadIdx.y;
  const int c0 = blockIdx.x * 32, r0 = blockIdx.y * 32;
#pragma unroll
  for (int k = 0; k < 4; ++k)
    t[ty + 8 * k][tx] = in[(size_t)(r0 + ty + 8 * k) * C + c0 + tx];
  __syncthreads();
#pragma unroll
  for (int k = 0; k < 4; ++k)
    out[(size_t)(c0 + ty + 8 * k) * R + r0 + tx] = f2bf(t[tx][ty + 8 * k]);
}

// ---------------------------------------------------------------------------
// bf16 MFMA GEMM, m97-style: C[M x TNxgrid] = A[M x K] * Bt[N x K]^T
// Tile 128(M) x TN(N), BK=32, 256 threads = 4 waves.
//   TN==128: waves 2x2, each 64x64 (4x4 frags)
//   TN==64 : waves 4x1 on M, each 32x64 (2x4 frags)
// Staging: global_load_lds dwordx4, store-side XOR swizzle
//   (chunk_phys = chunk_log ^ ((row>>1)&3)) so frag ds_read_b128 is 2-way
//   bank-aliased (free). LDS rows unpadded [row][32] u16 (64 B).
// ACT==1: softplus(C+bias). SPLITK>1: atomicAdd into pre-zeroed C.
// ---------------------------------------------------------------------------
template<int ACT, int SPLITK, int TN>
__global__ __launch_bounds__(256) void mgemm(
    const u16* __restrict__ A, int lda,
    const u16* __restrict__ Bt, int ldb,
    const float* __restrict__ bias,
    float* __restrict__ C, int ldc, int K)
{
  constexpr int WI = (TN == 128) ? 4 : 2;   // a-frags per wave
  __shared__ u16 Al[128 * 32];
  __shared__ u16 Bl[TN * 32];
  const int tid = threadIdx.x;
  const int bm = blockIdx.y * 128;
  const int bn = blockIdx.x * TN;
  const int lane = tid & 63;
  const int w = tid >> 6;
  const int wm = (TN == 128) ? (w & 1) * 64 : w * 32;
  const int wn = (TN == 128) ? (w >> 1) * 64 : 0;
  const int quad = lane >> 4;
  const int lm = lane & 15;

  const int Kper = K / SPLITK;
  const int k_beg = blockIdx.z * Kper;

  // staging source pointers (per lane). Logical k-chunk is swizzled so the
  // fixed linear LDS dest (lane*16B) receives the swizzled layout.
  const int clog8 = (((lane & 3) ^ ((lane >> 3) & 3)) << 3);  // u16 offset
  const int rA = w * 32 + (lane >> 2);
  const int rB = ((TN == 128) ? w * 32 : w * 16) + (lane >> 2);
  const u16* gA0 = A + (size_t)(bm + rA) * lda + k_beg + clog8;
  const u16* gA1 = gA0 + (size_t)16 * lda;
  const u16* gB0 = Bt + (size_t)(bn + rB) * ldb + k_beg + clog8;
  const u16* gB1 = gB0 + (size_t)16 * ldb;
  u16* lA0 = &Al[(w * 32) * 32];
  u16* lA1 = &Al[(w * 32 + 16) * 32];
  u16* lB0 = &Bl[(((TN == 128) ? w * 32 : w * 16)) * 32];
  u16* lB1 = &Bl[(w * 32 + 16) * 32];   // TN==128 only

  // frag read offset: physical chunk = quad ^ ((lm>>1)&3)
  const int cph8 = ((quad ^ ((lm >> 1) & 3)) << 3);

  f32x4 acc[WI][4] = {};

  for (int ks = 0; ks < Kper; ks += 32) {
    gload_lds16(gA0, lA0);
    gload_lds16(gA1, lA1);
    gload_lds16(gB0, lB0);
    if (TN == 128) gload_lds16(gB1, lB1);
    gA0 += 32; gA1 += 32; gB0 += 32; gB1 += 32;
    __syncthreads();

    short8 a[WI], b[4];
#pragma unroll
    for (int i = 0; i < WI; ++i)
      a[i] = *(const short8*)&Al[(wm + i * 16 + lm) * 32 + cph8];
#pragma unroll
    for (int j = 0; j < 4; ++j)
      b[j] = *(const short8*)&Bl[(wn + j * 16 + lm) * 32 + cph8];
#pragma unroll
    for (int i = 0; i < WI; ++i)
#pragma unroll
      for (int j = 0; j < 4; ++j)
        acc[i][j] = __builtin_amdgcn_mfma_f32_16x16x32_bf16(a[i], b[j], acc[i][j], 0, 0, 0);
    __syncthreads();
  }

#pragma unroll
  for (int i = 0; i < WI; ++i) {
#pragma unroll
    for (int r = 0; r < 4; ++r) {
      const int row = bm + wm + i * 16 + quad * 4 + r;
      float* cp = C + (size_t)row * ldc;
#pragma unroll
      for (int j = 0; j < 4; ++j) {
        const int col = bn + wn + j * 16 + lm;
        float v = acc[i][j][r];
        if (ACT == 1) v = softplus_f(v + bias[col]);
        if (SPLITK > 1) atomicAdd(&cp[col], v);
        else cp[col] = v;
      }
    }
  }
}

// ---------------------------------------------------------------------------
// Depthwise causal conv (k=4) + bias + SiLU. Reads XV fp32, writes XS bf16.
// ---------------------------------------------------------------------------
__global__ __launch_bounds__(256) void conv_silu_kernel(
    const float* __restrict__ XV, const float* __restrict__ cw,
    const float* __restrict__ cb, u16* __restrict__ XSb)
{
  const int idx = blockIdx.x * 256 + threadIdx.x;   // over B*L*DI
  const int d = idx & (DI - 1);
  const int bl = idx >> 11;
  const int l = bl & (LSEQ - 1);
  const float w0 = cw[d * 4 + 0], w1 = cw[d * 4 + 1];
  const float w2 = cw[d * 4 + 2], w3 = cw[d * 4 + 3];
  const float* p = XV + (size_t)idx;
  float acc = cb[d];
  acc = fmaf(w3, p[0], acc);
  if (l >= 1) acc = fmaf(w2, p[-DI], acc);
  if (l >= 2) acc = fmaf(w1, p[-2 * DI], acc);
  if (l >= 3) acc = fmaf(w0, p[-3 * DI], acc);
  XSb[idx] = f2bf(silu_f(acc));
}

// ---------------------------------------------------------------------------
// SSMB[:, 0:64] fp32 -> bf16 [2048][64]
// ---------------------------------------------------------------------------
__global__ __launch_bounds__(256) void slice_dt_bf16(
    const float* __restrict__ SSMB, u16* __restrict__ SBdt)
{
  const int t = blockIdx.x * 256 + threadIdx.x;   // over 2048*64
  const int m = t >> 6;
  const int c = t & 63;
  SBdt[t] = f2bf(SSMB[m * SSMP + c]);
}

// ---------------------------------------------------------------------------
// Chunked parallel scan, register-state version (one thread per (b,chunk,d)).
// ---------------------------------------------------------------------------
__global__ __launch_bounds__(256) void scan_pass1(
    const float* __restrict__ DELTA, const u16* __restrict__ XSb,
    const float* __restrict__ SSMB, const float* __restrict__ A_log,
    float* __restrict__ AGG_A, float* __restrict__ AGG_H)
{
  __shared__ float Bs[CHUNK * 16];
  const int tid = threadIdx.x;
  const int db = blockIdx.x & 7;
  const int c  = (blockIdx.x >> 3) & (NCHUNK - 1);
  const int b  = blockIdx.x >> 8;
  const int d  = db * 256 + tid;
  const int l0 = c * CHUNK;

  for (int i = tid; i < CHUNK * 16; i += 256) {
    const int l = i >> 4, n = i & 15;
    Bs[i] = SSMB[((size_t)(b * LSEQ + l0 + l)) * SSMP + DTR + n];
  }
  __syncthreads();

  float An[16];
  {
    const float* ar = A_log + d * 16;
#pragma unroll
    for (int n = 0; n < 16; ++n) An[n] = -__expf(ar[n]);
  }

  float h[16];
#pragma unroll
  for (int n = 0; n < 16; ++n) h[n] = 0.f;
  float S = 0.f;

  const float* dp = DELTA + ((size_t)(b * LSEQ + l0)) * DI + d;
  const u16*   xp = XSb   + ((size_t)(b * LSEQ + l0)) * DI + d;

  for (int l = 0; l < CHUNK; ++l) {
    const float delta = *dp; dp += DI;
    const float xv = bf2f(*xp); xp += DI;
    S += delta;
    const float dt = delta * xv;
    const f32x4 b0 = *(const f32x4*)&Bs[l * 16];
    const f32x4 b1 = *(const f32x4*)&Bs[l * 16 + 4];
    const f32x4 b2 = *(const f32x4*)&Bs[l * 16 + 8];
    const f32x4 b3 = *(const f32x4*)&Bs[l * 16 + 12];
#pragma unroll
    for (int n = 0; n < 16; ++n) {
      const float Bv = (n < 4) ? b0[n & 3] : (n < 8) ? b1[n & 3] : (n < 12) ? b2[n & 3] : b3[n & 3];
      const float dA = __expf(delta * An[n]);
      h[n] = fmaf(dA, h[n], Bv * dt);
    }
  }

  const size_t base = (((size_t)(b * NCHUNK + c) * DI + d) << 4);
  f32x4 oa[4], oh[4];
#pragma unroll
  for (int q = 0; q < 4; ++q) {
#pragma unroll
    for (int r = 0; r < 4; ++r) {
      oa[q][r] = __expf(An[q * 4 + r] * S);
      oh[q][r] = h[q * 4 + r];
    }
    *(f32x4*)&AGG_A[base + q * 4] = oa[q];
    *(f32x4*)&AGG_H[base + q * 4] = oh[q];
  }
}

// In-place prefix over chunks: AGG_H[ai] <- exclusive prefix (h_init).
__global__ __launch_bounds__(256) void scan_pass2(
    const float* __restrict__ AGG_A, float* __restrict__ AGG_H)
{
  const int t = blockIdx.x * 256 + threadIdx.x;   // over B*DI*NSTATE
  const int dn = t & (DI * NSTATE - 1);
  const int b = t >> 15;
  size_t ai = (size_t)b * NCHUNK * DI * NSTATE + dn;
  const size_t stride = (size_t)DI * NSTATE;
  float h = 0.f;
#pragma unroll
  for (int c = 0; c < NCHUNK; ++c) {
    const float a = AGG_A[ai];
    const float hp = AGG_H[ai];
    AGG_H[ai] = h;
    h = fmaf(a, h, hp);
    ai += stride;
  }
}

__global__ __launch_bounds__(256) void scan_pass3(
    const float* __restrict__ DELTA, const u16* __restrict__ XSb,
    const float* __restrict__ SSMB, const float* __restrict__ A_log,
    const float* __restrict__ Dp, const float* __restrict__ HINIT,
    u16* __restrict__ Yb)
{
  __shared__ float Bs[CHUNK * 16];
  __shared__ float Cs[CHUNK * 16];
  const int tid = threadIdx.x;
  const int db = blockIdx.x & 7;
  const int c  = (blockIdx.x >> 3) & (NCHUNK - 1);
  const int b  = blockIdx.x >> 8;
  const int d  = db * 256 + tid;
  const int l0 = c * CHUNK;

  for (int i = tid; i < CHUNK * 16; i += 256) {
    const int l = i >> 4, n = i & 15;
    const size_t row = ((size_t)(b * LSEQ + l0 + l)) * SSMP;
    Bs[i] = SSMB[row + DTR + n];
    Cs[i] = SSMB[row + DTR + NSTATE + n];
  }
  __syncthreads();

  float An[16];
  {
    const float* ar = A_log + d * 16;
#pragma unroll
    for (int n = 0; n < 16; ++n) An[n] = -__expf(ar[n]);
  }
  const float Dd = Dp[d];

  const size_t base = (((size_t)(b * NCHUNK + c) * DI + d) << 4);
  float h[16];
#pragma unroll
  for (int q = 0; q < 4; ++q) {
    const f32x4 hv = *(const f32x4*)&HINIT[base + q * 4];
#pragma unroll
    for (int r = 0; r < 4; ++r) h[q * 4 + r] = hv[r];
  }

  const float* dp = DELTA + ((size_t)(b * LSEQ + l0)) * DI + d;
  const u16*   xp = XSb   + ((size_t)(b * LSEQ + l0)) * DI + d;
  u16*         yp = Yb    + ((size_t)(b * LSEQ + l0)) * DI + d;

  for (int l = 0; l < CHUNK; ++l) {
    const float delta = *dp; dp += DI;
    const float xv = bf2f(*xp); xp += DI;
    const float dt = delta * xv;
    float y = xv * Dd;
    const f32x4 b0 = *(const f32x4*)&Bs[l * 16];
    const f32x4 b1 = *(const f32x4*)&Bs[l * 16 + 4];
    const f32x4 b2 = *(const f32x4*)&Bs[l * 16 + 8];
    const f32x4 b3 = *(const f32x4*)&Bs[l * 16 + 12];
    const f32x4 c0 = *(const f32x4*)&Cs[l * 16];
    const f32x4 c1 = *(const f32x4*)&Cs[l * 16 + 4];
    const f32x4 c2 = *(const f32x4*)&Cs[l * 16 + 8];
    const f32x4 c3 = *(const f32x4*)&Cs[l * 16 + 12];
#pragma unroll
    for (int n = 0; n < 16; ++n) {
      const float Bv = (n < 4) ? b0[n & 3] : (n < 8) ? b1[n & 3] : (n < 12) ? b2[n & 3] : b3[n & 3];
      const float Cv = (n < 4) ? c0[n & 3] : (n < 8) ? c1[n & 3] : (n < 12) ? c2[n & 3] : c3[n & 3];
      const float dA = __expf(delta * An[n]);
      h[n] = fmaf(dA, h[n], Bv * dt);
      y = fmaf(h[n], Cv, y);
    }
    *yp = f2bf(y); yp += DI;
  }
}

// ---------------------------------------------------------------------------
extern "C" void kernel_launch(void* const* d_in, const int* in_sizes, int n_in,
                              void* d_out, int out_size, void* d_ws, size_t ws_size,
                              hipStream_t stream)
{
  const float* x      = (const float*)d_in[0];
  const float* W_in   = (const float*)d_in[1];
  const float* conv_w = (const float*)d_in[2];
  const float* conv_b = (const float*)d_in[3];
  const float* W_x    = (const float*)d_in[4];
  const float* W_dt   = (const float*)d_in[5];
  const float* b_dt   = (const float*)d_in[6];
  const float* A_log  = (const float*)d_in[7];
  const float* Dp     = (const float*)d_in[8];
  const float* W_out  = (const float*)d_in[9];
  float* out = (float*)d_out;
  char* W = (char*)d_ws;

  const size_t MB = 1u << 20;
  // byte layout (46 MB total), time-multiplexed (see R3/R4 notes):
  float* XV    = (float*)(W + 0);
  float* AGG_A = (float*)(W + 0);
  float* AGG_H = (float*)(W + 8 * MB);
  u16*   Yb    = (u16*)  (W + 0);
  u16*   x_bf  = (u16*)  (W + 16 * MB);
  u16*   WinT  = (u16*)  (W + 20 * MB);
  float* DELTA = (float*)(W + 16 * MB);
  u16*   XSb   = (u16*)  (W + 32 * MB);
  float* SSMB  = (float*)(W + 40 * MB);
  u16*   WoutT = (u16*)  (W + 41 * MB);
  u16*   WxT   = (u16*)  (W + 45 * MB);
  u16*   WdtT  = (u16*)  (W + 45 * MB + 512 * 1024);
  u16*   SBdt  = (u16*)  (W + 45 * MB + 768 * 1024);

  dim3 blk(256);
  dim3 tblk(32, 8);

  // 0) input converts / weight transposes (all bf16, K-contiguous)
  cvt_bf16<<<dim3(2048), blk, 0, stream>>>(x, x_bf);
  transpose_bf16<<<dim3(64, 32), tblk, 0, stream>>>(W_in, WinT, 1024, 2048);
  hipMemsetAsync(WxT, 0, 128 * 2048 * sizeof(u16), stream);
  transpose_bf16<<<dim3(3, 64), tblk, 0, stream>>>(W_x, WxT, 2048, 96);
  transpose_bf16<<<dim3(64, 2), tblk, 0, stream>>>(W_dt, WdtT, 64, 2048);
  transpose_bf16<<<dim3(32, 64), tblk, 0, stream>>>(W_out, WoutT, 2048, 1024);

  // 1) xv = x @ W_in  (M=2048 N=2048 K=1024), TN=64 -> 512 blocks
  mgemm<0, 1, 64><<<dim3(32, 16, 1), blk, 0, stream>>>(
      x_bf, DMODEL, WinT, DMODEL, nullptr, XV, DI, DMODEL);

  // 2) conv + silu -> XSb bf16
  conv_silu_kernel<<<dim3((BATCH * LSEQ * DI) / 256), blk, 0, stream>>>(
      XV, conv_w, conv_b, XSb);

  // 3) ssm = xs @ W_x  (M=2048 N=128pad K=2048), splitK=16 -> 256 blocks
  hipMemsetAsync(SSMB, 0, MROWS * SSMP * sizeof(float), stream);
  mgemm<0, 16, 128><<<dim3(1, 16, 16), blk, 0, stream>>>(
      XSb, DI, WxT, DI, nullptr, SSMB, SSMP, DI);

  // 4) delta = softplus(ssm[:, :64] @ W_dt + b_dt)  (K=64) -> DELTA fp32
  slice_dt_bf16<<<dim3(512), blk, 0, stream>>>(SSMB, SBdt);
  mgemm<1, 1, 128><<<dim3(16, 16, 1), blk, 0, stream>>>(
      SBdt, DTR, WdtT, DTR, b_dt, DELTA, DI, DTR);

  // 5) chunked scan (register-state)
  scan_pass1<<<dim3(BATCH * NCHUNK * (DI / 256)), blk, 0, stream>>>(
      DELTA, XSb, SSMB, A_log, AGG_A, AGG_H);
  scan_pass2<<<dim3((BATCH * DI * NSTATE) / 256), blk, 0, stream>>>(
      AGG_A, AGG_H);
  scan_pass3<<<dim3(BATCH * NCHUNK * (DI / 256)), blk, 0, stream>>>(
      DELTA, XSb, SSMB, A_log, Dp, AGG_H, Yb);

  // 6) out = y @ W_out  (M=2048 N=1024 K=2048), TN=64 splitK=2 -> 512 blocks
  hipMemsetAsync(out, 0, (size_t)MROWS * DMODEL * sizeof(float), stream);
  mgemm<0, 2, 64><<<dim3(16, 16, 2), blk, 0, stream>>>(
      Yb, DI, WoutT, DI, nullptr, out, DMODEL, DI);
}

// Round 6
// 244.281 us; speedup vs baseline: 5.5847x; 1.0809x over previous
//
#include <hip/hip_runtime.h>
#include <math.h>

// Problem constants
#define BATCH   2
#define LSEQ    1024
#define DMODEL  1024
#define DI      2048      // D_INNER
#define NSTATE  16
#define DTR     64        // DT_RANK
#define SSMP    128       // padded ssm width (96 -> 128); B at +64, C at +80
#define MROWS   2048      // BATCH*LSEQ
#define CHUNK   32
#define NCHUNK  32        // LSEQ / CHUNK

typedef unsigned short u16;
typedef __attribute__((ext_vector_type(8))) short short8;   // 8 bf16 (4 VGPRs)
typedef __attribute__((ext_vector_type(4))) float f32x4;

__device__ __forceinline__ float silu_f(float x) {
  return x / (1.f + __expf(-x));
}
__device__ __forceinline__ float softplus_f(float x) {
  return fmaxf(x, 0.f) + log1pf(__expf(-fabsf(x)));
}
__device__ __forceinline__ u16 f2bf(float f) {   // RNE
  unsigned u = __float_as_uint(f);
  return (u16)((u + 0x7fffu + ((u >> 16) & 1u)) >> 16);
}
__device__ __forceinline__ float bf2f(u16 v) {
  return __uint_as_float(((unsigned)v) << 16);
}

// async global -> LDS, 16 B per lane; LDS dest = wave-uniform base + lane*16
__device__ __forceinline__ void gload_lds16(const u16* g, u16* l) {
  __builtin_amdgcn_global_load_lds(
      (const __attribute__((address_space(1))) unsigned int*)(const void*)g,
      (__attribute__((address_space(3))) unsigned int*)(void*)l, 16, 0, 0);
}

// ---------------------------------------------------------------------------
// Fused preprocessing: one kernel, block-range dispatch.
//   [0,2048)        : cvt x fp32->bf16 (2M elems, x4 vec)
//   [2048,4096)     : transpose W_in   [1024][2048] -> WinT  [2048][1024]
//   [4096,4288)     : transpose W_x    [2048][96]   -> WxT   [96 of 128][2048]
//   [4288,4352)     : zero WxT rows 96..127
//   [4352,4480)     : transpose W_dt   [64][2048]   -> WdtT  [2048][64]
//   [4480,6528)     : transpose W_out  [2048][1024] -> WoutT [1024][2048]
// ---------------------------------------------------------------------------
__device__ __forceinline__ void transpose_dev(
    float (*t)[33], const float* __restrict__ in, u16* __restrict__ out,
    int R, int C, int bx, int by, int tid)
{
  const int tx = tid & 31, ty = tid >> 5;          // 32 x 8
  const int c0 = bx * 32, r0 = by * 32;
#pragma unroll
  for (int k = 0; k < 4; ++k)
    t[ty + 8 * k][tx] = in[(size_t)(r0 + ty + 8 * k) * C + c0 + tx];
  __syncthreads();
#pragma unroll
  for (int k = 0; k < 4; ++k)
    out[(size_t)(c0 + ty + 8 * k) * R + r0 + tx] = f2bf(t[tx][ty + 8 * k]);
}

__global__ __launch_bounds__(256) void prep_kernel(
    const float* __restrict__ x, const float* __restrict__ W_in,
    const float* __restrict__ W_x, const float* __restrict__ W_dt,
    const float* __restrict__ W_out,
    u16* __restrict__ x_bf, u16* __restrict__ WinT, u16* __restrict__ WxT,
    u16* __restrict__ WdtT, u16* __restrict__ WoutT)
{
  __shared__ float ts[32][33];
  const int tid = threadIdx.x;
  int bi = blockIdx.x;
  if (bi < 2048) {                      // cvt x
    const int i = (bi * 256 + tid) * 4;
    float4 v = *(const float4*)(x + i);
    ushort4 o;
    o.x = f2bf(v.x); o.y = f2bf(v.y); o.z = f2bf(v.z); o.w = f2bf(v.w);
    *(ushort4*)(x_bf + i) = o;
    return;
  }
  bi -= 2048;
  if (bi < 2048) {                      // W_in: grid (64, 32)
    transpose_dev(ts, W_in, WinT, 1024, 2048, bi & 63, bi >> 6, tid);
    return;
  }
  bi -= 2048;
  if (bi < 192) {                       // W_x: grid (3, 64)
    transpose_dev(ts, W_x, WxT, 2048, 96, bi % 3, bi / 3, tid);
    return;
  }
  bi -= 192;
  if (bi < 64) {                        // zero WxT rows 96..127 (64K u16)
    const int i = (bi * 256 + tid) * 4;
    *(ushort4*)(WxT + 96 * 2048 + i) = make_ushort4(0, 0, 0, 0);
    return;
  }
  bi -= 64;
  if (bi < 128) {                       // W_dt: grid (64, 2)
    transpose_dev(ts, W_dt, WdtT, 64, 2048, bi & 63, bi >> 6, tid);
    return;
  }
  bi -= 128;
  {                                     // W_out: grid (32, 64)
    transpose_dev(ts, W_out, WoutT, 2048, 1024, bi & 31, bi >> 5, tid);
  }
}

// ---------------------------------------------------------------------------
// bf16 MFMA GEMM, m97-style: C[M x TNxgrid] = A[M x K] * Bt[N x K]^T
// Tile 128(M) x TN(N), BK=32, 256 threads = 4 waves.
//   TN==128: waves 2x2, each 64x64 (4x4 frags)
//   TN==64 : waves 4x1 on M, each 32x64 (2x4 frags)
// Staging: global_load_lds dwordx4 with store-side XOR chunk swizzle
//   (phys = log ^ ((row>>1)&3)); frag ds_read_b128 covers a contiguous 1KB
//   LDS region per wave -> conflict-free.
// ACT==1: softplus(C+bias).
// SPLITK>1: DETERMINISTIC partials -> C + z * (gridDim.y*128*ldc), plain store.
// ---------------------------------------------------------------------------
template<int ACT, int SPLITK, int TN>
__global__ __launch_bounds__(256) void mgemm(
    const u16* __restrict__ A, int lda,
    const u16* __restrict__ Bt, int ldb,
    const float* __restrict__ bias,
    float* __restrict__ C, int ldc, int K)
{
  constexpr int WI = (TN == 128) ? 4 : 2;   // a-frags per wave
  __shared__ u16 Al[128 * 32];
  __shared__ u16 Bl[TN * 32];
  const int tid = threadIdx.x;
  const int bm = blockIdx.y * 128;
  const int bn = blockIdx.x * TN;
  const int lane = tid & 63;
  const int w = tid >> 6;
  const int wm = (TN == 128) ? (w & 1) * 64 : w * 32;
  const int wn = (TN == 128) ? (w >> 1) * 64 : 0;
  const int quad = lane >> 4;
  const int lm = lane & 15;

  const int Kper = K / SPLITK;
  const int k_beg = blockIdx.z * Kper;

  const int clog8 = (((lane & 3) ^ ((lane >> 3) & 3)) << 3);  // u16 offset
  const int rA = w * 32 + (lane >> 2);
  const int rB = ((TN == 128) ? w * 32 : w * 16) + (lane >> 2);
  const u16* gA0 = A + (size_t)(bm + rA) * lda + k_beg + clog8;
  const u16* gA1 = gA0 + (size_t)16 * lda;
  const u16* gB0 = Bt + (size_t)(bn + rB) * ldb + k_beg + clog8;
  const u16* gB1 = gB0 + (size_t)16 * ldb;
  u16* lA0 = &Al[(w * 32) * 32];
  u16* lA1 = &Al[(w * 32 + 16) * 32];
  u16* lB0 = &Bl[(((TN == 128) ? w * 32 : w * 16)) * 32];
  u16* lB1 = &Bl[(w * 32 + 16) * 32];   // TN==128 only

  const int cph8 = ((quad ^ ((lm >> 1) & 3)) << 3);

  f32x4 acc[WI][4] = {};

  for (int ks = 0; ks < Kper; ks += 32) {
    gload_lds16(gA0, lA0);
    gload_lds16(gA1, lA1);
    gload_lds16(gB0, lB0);
    if (TN == 128) gload_lds16(gB1, lB1);
    gA0 += 32; gA1 += 32; gB0 += 32; gB1 += 32;
    __syncthreads();

    short8 a[WI], b[4];
#pragma unroll
    for (int i = 0; i < WI; ++i)
      a[i] = *(const short8*)&Al[(wm + i * 16 + lm) * 32 + cph8];
#pragma unroll
    for (int j = 0; j < 4; ++j)
      b[j] = *(const short8*)&Bl[(wn + j * 16 + lm) * 32 + cph8];
#pragma unroll
    for (int i = 0; i < WI; ++i)
#pragma unroll
      for (int j = 0; j < 4; ++j)
        acc[i][j] = __builtin_amdgcn_mfma_f32_16x16x32_bf16(a[i], b[j], acc[i][j], 0, 0, 0);
    __syncthreads();
  }

  float* Cz = C;
  if (SPLITK > 1)
    Cz += (size_t)blockIdx.z * gridDim.y * 128 * ldc;

#pragma unroll
  for (int i = 0; i < WI; ++i) {
#pragma unroll
    for (int r = 0; r < 4; ++r) {
      const int row = bm + wm + i * 16 + quad * 4 + r;
      float* cp = Cz + (size_t)row * ldc;
#pragma unroll
      for (int j = 0; j < 4; ++j) {
        const int col = bn + wn + j * 16 + lm;
        float v = acc[i][j][r];
        if (ACT == 1) v = softplus_f(v + bias[col]);
        cp[col] = v;
      }
    }
  }
}

// ---------------------------------------------------------------------------
// Reduce gemm3's 16 split-K partials -> SSMB fp32, and emit bf16 dt slice.
// ---------------------------------------------------------------------------
__global__ __launch_bounds__(256) void reduce3_slice(
    const float* __restrict__ P3, float* __restrict__ SSMB,
    u16* __restrict__ SBdt)
{
  const int t = blockIdx.x * 256 + threadIdx.x;   // over 2048*128
  float s = 0.f;
#pragma unroll
  for (int z = 0; z < 16; ++z) s += P3[(size_t)z * (MROWS * SSMP) + t];
  SSMB[t] = s;
  const int n = t & (SSMP - 1), m = t >> 7;
  if (n < DTR) SBdt[m * DTR + n] = f2bf(s);
}

// ---------------------------------------------------------------------------
// Reduce gemm6's 2 split-K partials -> d_out (writes every element).
// ---------------------------------------------------------------------------
__global__ __launch_bounds__(256) void reduce6(
    const float* __restrict__ P6, float* __restrict__ out)
{
  const int i = (blockIdx.x * 256 + threadIdx.x) * 4;   // over 2M
  float4 a = *(const float4*)(P6 + i);
  float4 b = *(const float4*)(P6 + (size_t)MROWS * DMODEL + i);
  a.x += b.x; a.y += b.y; a.z += b.z; a.w += b.w;
  *(float4*)(out + i) = a;
}

// ---------------------------------------------------------------------------
// Depthwise causal conv (k=4) + bias + SiLU. Reads XV fp32, writes XS bf16.
// ---------------------------------------------------------------------------
__global__ __launch_bounds__(256) void conv_silu_kernel(
    const float* __restrict__ XV, const float* __restrict__ cw,
    const float* __restrict__ cb, u16* __restrict__ XSb)
{
  const int idx = blockIdx.x * 256 + threadIdx.x;   // over B*L*DI
  const int d = idx & (DI - 1);
  const int bl = idx >> 11;
  const int l = bl & (LSEQ - 1);
  const float w0 = cw[d * 4 + 0], w1 = cw[d * 4 + 1];
  const float w2 = cw[d * 4 + 2], w3 = cw[d * 4 + 3];
  const float* p = XV + (size_t)idx;
  float acc = cb[d];
  acc = fmaf(w3, p[0], acc);
  if (l >= 1) acc = fmaf(w2, p[-DI], acc);
  if (l >= 2) acc = fmaf(w1, p[-2 * DI], acc);
  if (l >= 3) acc = fmaf(w0, p[-3 * DI], acc);
  XSb[idx] = f2bf(silu_f(acc));
}

// ---------------------------------------------------------------------------
// Chunked parallel scan, register-state version (one thread per (b,chunk,d)).
// ---------------------------------------------------------------------------
__global__ __launch_bounds__(256) void scan_pass1(
    const float* __restrict__ DELTA, const u16* __restrict__ XSb,
    const float* __restrict__ SSMB, const float* __restrict__ A_log,
    float* __restrict__ AGG_A, float* __restrict__ AGG_H)
{
  __shared__ float Bs[CHUNK * 16];
  const int tid = threadIdx.x;
  const int db = blockIdx.x & 7;
  const int c  = (blockIdx.x >> 3) & (NCHUNK - 1);
  const int b  = blockIdx.x >> 8;
  const int d  = db * 256 + tid;
  const int l0 = c * CHUNK;

  for (int i = tid; i < CHUNK * 16; i += 256) {
    const int l = i >> 4, n = i & 15;
    Bs[i] = SSMB[((size_t)(b * LSEQ + l0 + l)) * SSMP + DTR + n];
  }
  __syncthreads();

  float An[16];
  {
    const float* ar = A_log + d * 16;
#pragma unroll
    for (int n = 0; n < 16; ++n) An[n] = -__expf(ar[n]);
  }

  float h[16];
#pragma unroll
  for (int n = 0; n < 16; ++n) h[n] = 0.f;
  float S = 0.f;

  const float* dp = DELTA + ((size_t)(b * LSEQ + l0)) * DI + d;
  const u16*   xp = XSb   + ((size_t)(b * LSEQ + l0)) * DI + d;

  for (int l = 0; l < CHUNK; ++l) {
    const float delta = *dp; dp += DI;
    const float xv = bf2f(*xp); xp += DI;
    S += delta;
    const float dt = delta * xv;
    const f32x4 b0 = *(const f32x4*)&Bs[l * 16];
    const f32x4 b1 = *(const f32x4*)&Bs[l * 16 + 4];
    const f32x4 b2 = *(const f32x4*)&Bs[l * 16 + 8];
    const f32x4 b3 = *(const f32x4*)&Bs[l * 16 + 12];
#pragma unroll
    for (int n = 0; n < 16; ++n) {
      const float Bv = (n < 4) ? b0[n & 3] : (n < 8) ? b1[n & 3] : (n < 12) ? b2[n & 3] : b3[n & 3];
      const float dA = __expf(delta * An[n]);
      h[n] = fmaf(dA, h[n], Bv * dt);
    }
  }

  const size_t base = (((size_t)(b * NCHUNK + c) * DI + d) << 4);
  f32x4 oa[4], oh[4];
#pragma unroll
  for (int q = 0; q < 4; ++q) {
#pragma unroll
    for (int r = 0; r < 4; ++r) {
      oa[q][r] = __expf(An[q * 4 + r] * S);
      oh[q][r] = h[q * 4 + r];
    }
    *(f32x4*)&AGG_A[base + q * 4] = oa[q];
    *(f32x4*)&AGG_H[base + q * 4] = oh[q];
  }
}

// In-place prefix over chunks: AGG_H[ai] <- exclusive prefix (h_init).
__global__ __launch_bounds__(256) void scan_pass2(
    const float* __restrict__ AGG_A, float* __restrict__ AGG_H)
{
  const int t = blockIdx.x * 256 + threadIdx.x;   // over B*DI*NSTATE
  const int dn = t & (DI * NSTATE - 1);
  const int b = t >> 15;
  size_t ai = (size_t)b * NCHUNK * DI * NSTATE + dn;
  const size_t stride = (size_t)DI * NSTATE;
  float h = 0.f;
#pragma unroll
  for (int c = 0; c < NCHUNK; ++c) {
    const float a = AGG_A[ai];
    const float hp = AGG_H[ai];
    AGG_H[ai] = h;
    h = fmaf(a, h, hp);
    ai += stride;
  }
}

__global__ __launch_bounds__(256) void scan_pass3(
    const float* __restrict__ DELTA, const u16* __restrict__ XSb,
    const float* __restrict__ SSMB, const float* __restrict__ A_log,
    const float* __restrict__ Dp, const float* __restrict__ HINIT,
    u16* __restrict__ Yb)
{
  __shared__ float Bs[CHUNK * 16];
  __shared__ float Cs[CHUNK * 16];
  const int tid = threadIdx.x;
  const int db = blockIdx.x & 7;
  const int c  = (blockIdx.x >> 3) & (NCHUNK - 1);
  const int b  = blockIdx.x >> 8;
  const int d  = db * 256 + tid;
  const int l0 = c * CHUNK;

  for (int i = tid; i < CHUNK * 16; i += 256) {
    const int l = i >> 4, n = i & 15;
    const size_t row = ((size_t)(b * LSEQ + l0 + l)) * SSMP;
    Bs[i] = SSMB[row + DTR + n];
    Cs[i] = SSMB[row + DTR + NSTATE + n];
  }
  __syncthreads();

  float An[16];
  {
    const float* ar = A_log + d * 16;
#pragma unroll
    for (int n = 0; n < 16; ++n) An[n] = -__expf(ar[n]);
  }
  const float Dd = Dp[d];

  const size_t base = (((size_t)(b * NCHUNK + c) * DI + d) << 4);
  float h[16];
#pragma unroll
  for (int q = 0; q < 4; ++q) {
    const f32x4 hv = *(const f32x4*)&HINIT[base + q * 4];
#pragma unroll
    for (int r = 0; r < 4; ++r) h[q * 4 + r] = hv[r];
  }

  const float* dp = DELTA + ((size_t)(b * LSEQ + l0)) * DI + d;
  const u16*   xp = XSb   + ((size_t)(b * LSEQ + l0)) * DI + d;
  u16*         yp = Yb    + ((size_t)(b * LSEQ + l0)) * DI + d;

  for (int l = 0; l < CHUNK; ++l) {
    const float delta = *dp; dp += DI;
    const float xv = bf2f(*xp); xp += DI;
    const float dt = delta * xv;
    float y = xv * Dd;
    const f32x4 b0 = *(const f32x4*)&Bs[l * 16];
    const f32x4 b1 = *(const f32x4*)&Bs[l * 16 + 4];
    const f32x4 b2 = *(const f32x4*)&Bs[l * 16 + 8];
    const f32x4 b3 = *(const f32x4*)&Bs[l * 16 + 12];
    const f32x4 c0 = *(const f32x4*)&Cs[l * 16];
    const f32x4 c1 = *(const f32x4*)&Cs[l * 16 + 4];
    const f32x4 c2 = *(const f32x4*)&Cs[l * 16 + 8];
    const f32x4 c3 = *(const f32x4*)&Cs[l * 16 + 12];
#pragma unroll
    for (int n = 0; n < 16; ++n) {
      const float Bv = (n < 4) ? b0[n & 3] : (n < 8) ? b1[n & 3] : (n < 12) ? b2[n & 3] : b3[n & 3];
      const float Cv = (n < 4) ? c0[n & 3] : (n < 8) ? c1[n & 3] : (n < 12) ? c2[n & 3] : c3[n & 3];
      const float dA = __expf(delta * An[n]);
      h[n] = fmaf(dA, h[n], Bv * dt);
      y = fmaf(h[n], Cv, y);
    }
    *yp = f2bf(y); yp += DI;
  }
}

// ---------------------------------------------------------------------------
extern "C" void kernel_launch(void* const* d_in, const int* in_sizes, int n_in,
                              void* d_out, int out_size, void* d_ws, size_t ws_size,
                              hipStream_t stream)
{
  const float* x      = (const float*)d_in[0];
  const float* W_in   = (const float*)d_in[1];
  const float* conv_w = (const float*)d_in[2];
  const float* conv_b = (const float*)d_in[3];
  const float* W_x    = (const float*)d_in[4];
  const float* W_dt   = (const float*)d_in[5];
  const float* b_dt   = (const float*)d_in[6];
  const float* A_log  = (const float*)d_in[7];
  const float* Dp     = (const float*)d_in[8];
  const float* W_out  = (const float*)d_in[9];
  float* out = (float*)d_out;
  char* W = (char*)d_ws;

  const size_t MB = 1u << 20;
  // byte layout (46 MB), time-multiplexed:
  // [0,16)  : XV fp32 (gemm1->conv)  ->  AGG_A[0,8)+AGG_H[8,16) (scan) -> Yb[0,8)
  // [16,32) : x_bf[16,20)+WinT[20,24) (prep->gemm1) -> P3 16MB (gemm3->reduce3)
  //           -> DELTA 16MB (gemm4->scan) -> P6 16MB (gemm6->reduce6)
  // [32,40) : XSb bf16
  // [40,41) : SSMB fp32 [2048][128]
  // [41,45) : WoutT
  // [45,46) : WxT[45,45.5) + WdtT[45.5,45.75) + SBdt[45.75,46)
  float* XV    = (float*)(W + 0);
  float* AGG_A = (float*)(W + 0);
  float* AGG_H = (float*)(W + 8 * MB);
  u16*   Yb    = (u16*)  (W + 0);
  u16*   x_bf  = (u16*)  (W + 16 * MB);
  u16*   WinT  = (u16*)  (W + 20 * MB);
  float* P3    = (float*)(W + 16 * MB);
  float* DELTA = (float*)(W + 16 * MB);
  float* P6    = (float*)(W + 16 * MB);
  u16*   XSb   = (u16*)  (W + 32 * MB);
  float* SSMB  = (float*)(W + 40 * MB);
  u16*   WoutT = (u16*)  (W + 41 * MB);
  u16*   WxT   = (u16*)  (W + 45 * MB);
  u16*   WdtT  = (u16*)  (W + 45 * MB + 512 * 1024);
  u16*   SBdt  = (u16*)  (W + 45 * MB + 768 * 1024);

  dim3 blk(256);

  // 0) fused preprocessing (cvt + 4 transposes + WxT pad-zero)
  prep_kernel<<<dim3(6528), blk, 0, stream>>>(
      x, W_in, W_x, W_dt, W_out, x_bf, WinT, WxT, WdtT, WoutT);

  // 1) xv = x @ W_in  (M=2048 N=2048 K=1024), TN=64 -> 512 blocks
  mgemm<0, 1, 64><<<dim3(32, 16, 1), blk, 0, stream>>>(
      x_bf, DMODEL, WinT, DMODEL, nullptr, XV, DI, DMODEL);

  // 2) conv + silu -> XSb bf16
  conv_silu_kernel<<<dim3((BATCH * LSEQ * DI) / 256), blk, 0, stream>>>(
      XV, conv_w, conv_b, XSb);

  // 3) ssm partials (M=2048 N=128pad K=2048, splitK=16 deterministic) -> P3
  mgemm<0, 16, 128><<<dim3(1, 16, 16), blk, 0, stream>>>(
      XSb, DI, WxT, DI, nullptr, P3, SSMP, DI);
  reduce3_slice<<<dim3(MROWS * SSMP / 256), blk, 0, stream>>>(P3, SSMB, SBdt);

  // 4) delta = softplus(ssm[:, :64] @ W_dt + b_dt)  (K=64) -> DELTA fp32
  mgemm<1, 1, 128><<<dim3(16, 16, 1), blk, 0, stream>>>(
      SBdt, DTR, WdtT, DTR, b_dt, DELTA, DI, DTR);

  // 5) chunked scan (register-state)
  scan_pass1<<<dim3(BATCH * NCHUNK * (DI / 256)), blk, 0, stream>>>(
      DELTA, XSb, SSMB, A_log, AGG_A, AGG_H);
  scan_pass2<<<dim3((BATCH * DI * NSTATE) / 256), blk, 0, stream>>>(
      AGG_A, AGG_H);
  scan_pass3<<<dim3(BATCH * NCHUNK * (DI / 256)), blk, 0, stream>>>(
      DELTA, XSb, SSMB, A_log, Dp, AGG_H, Yb);

  // 6) out partials (M=2048 N=1024 K=2048, TN=64 splitK=2) -> P6, then reduce
  mgemm<0, 2, 64><<<dim3(16, 16, 2), blk, 0, stream>>>(
      Yb, DI, WoutT, DI, nullptr, P6, DMODEL, DI);
  reduce6<<<dim3(MROWS * DMODEL / 1024), blk, 0, stream>>>(P6, out);
}

// Round 7
// 237.903 us; speedup vs baseline: 5.7344x; 1.0268x over previous
//
#include <hip/hip_runtime.h>
#include <math.h>

// Problem constants
#define BATCH   2
#define LSEQ    1024
#define DMODEL  1024
#define DI      2048      // D_INNER
#define NSTATE  16
#define DTR     64        // DT_RANK
#define SSMP    128       // padded ssm width (96 -> 128); B at +64, C at +80
#define MROWS   2048      // BATCH*LSEQ
#define CHUNK   32
#define NCHUNK  32        // LSEQ / CHUNK

typedef unsigned short u16;
typedef __attribute__((ext_vector_type(8))) short short8;   // 8 bf16 (4 VGPRs)
typedef __attribute__((ext_vector_type(4))) float f32x4;

__device__ __forceinline__ float silu_f(float x) {
  return x / (1.f + __expf(-x));
}
__device__ __forceinline__ float softplus_f(float x) {
  return fmaxf(x, 0.f) + log1pf(__expf(-fabsf(x)));
}
__device__ __forceinline__ u16 f2bf(float f) {   // RNE
  unsigned u = __float_as_uint(f);
  return (u16)((u + 0x7fffu + ((u >> 16) & 1u)) >> 16);
}
__device__ __forceinline__ float bf2f(u16 v) {
  return __uint_as_float(((unsigned)v) << 16);
}

// async global -> LDS, 16 B per lane; LDS dest = wave-uniform base + lane*16
__device__ __forceinline__ void gload_lds16(const u16* g, u16* l) {
  __builtin_amdgcn_global_load_lds(
      (const __attribute__((address_space(1))) unsigned int*)(const void*)g,
      (__attribute__((address_space(3))) unsigned int*)(void*)l, 16, 0, 0);
}

// ---------------------------------------------------------------------------
// Fused preprocessing: one kernel, block-range dispatch.
//   [0,2048)        : cvt x fp32->bf16 (2M elems, x4 vec)
//   [2048,4096)     : transpose W_in   [1024][2048] -> WinT  [2048][1024]
//   [4096,4288)     : transpose W_x    [2048][96]   -> WxT   [96 of 128][2048]
//   [4288,4352)     : zero WxT rows 96..127
//   [4352,4480)     : transpose W_dt   [64][2048]   -> WdtT  [2048][64]
//   [4480,6528)     : transpose W_out  [2048][1024] -> WoutT [1024][2048]
// ---------------------------------------------------------------------------
__device__ __forceinline__ void transpose_dev(
    float (*t)[33], const float* __restrict__ in, u16* __restrict__ out,
    int R, int C, int bx, int by, int tid)
{
  const int tx = tid & 31, ty = tid >> 5;          // 32 x 8
  const int c0 = bx * 32, r0 = by * 32;
#pragma unroll
  for (int k = 0; k < 4; ++k)
    t[ty + 8 * k][tx] = in[(size_t)(r0 + ty + 8 * k) * C + c0 + tx];
  __syncthreads();
#pragma unroll
  for (int k = 0; k < 4; ++k)
    out[(size_t)(c0 + ty + 8 * k) * R + r0 + tx] = f2bf(t[tx][ty + 8 * k]);
}

__global__ __launch_bounds__(256) void prep_kernel(
    const float* __restrict__ x, const float* __restrict__ W_in,
    const float* __restrict__ W_x, const float* __restrict__ W_dt,
    const float* __restrict__ W_out,
    u16* __restrict__ x_bf, u16* __restrict__ WinT, u16* __restrict__ WxT,
    u16* __restrict__ WdtT, u16* __restrict__ WoutT)
{
  __shared__ float ts[32][33];
  const int tid = threadIdx.x;
  int bi = blockIdx.x;
  if (bi < 2048) {                      // cvt x
    const int i = (bi * 256 + tid) * 4;
    float4 v = *(const float4*)(x + i);
    ushort4 o;
    o.x = f2bf(v.x); o.y = f2bf(v.y); o.z = f2bf(v.z); o.w = f2bf(v.w);
    *(ushort4*)(x_bf + i) = o;
    return;
  }
  bi -= 2048;
  if (bi < 2048) {                      // W_in: grid (64, 32)
    transpose_dev(ts, W_in, WinT, 1024, 2048, bi & 63, bi >> 6, tid);
    return;
  }
  bi -= 2048;
  if (bi < 192) {                       // W_x: grid (3, 64)
    transpose_dev(ts, W_x, WxT, 2048, 96, bi % 3, bi / 3, tid);
    return;
  }
  bi -= 192;
  if (bi < 64) {                        // zero WxT rows 96..127 (64K u16)
    const int i = (bi * 256 + tid) * 4;
    *(ushort4*)(WxT + 96 * 2048 + i) = make_ushort4(0, 0, 0, 0);
    return;
  }
  bi -= 64;
  if (bi < 128) {                       // W_dt: grid (64, 2)
    transpose_dev(ts, W_dt, WdtT, 64, 2048, bi & 63, bi >> 6, tid);
    return;
  }
  bi -= 128;
  {                                     // W_out: grid (32, 64)
    transpose_dev(ts, W_out, WoutT, 2048, 1024, bi & 31, bi >> 5, tid);
  }
}

// ---------------------------------------------------------------------------
// bf16 MFMA GEMM, m97-style: C[M x TNxgrid] = A[M x K] * Bt[N x K]^T
// Tile 128(M) x TN(N), BK=32, 256 threads = 4 waves.
//   TN==128: waves 2x2, each 64x64 (4x4 frags)
//   TN==64 : waves 4x1 on M, each 32x64 (2x4 frags)
// Staging: global_load_lds dwordx4 with store-side XOR chunk swizzle
//   (phys = log ^ ((row>>1)&3)); frag ds_read_b128 conflict-free.
// ACT==1: softplus(C+bias).
// SPLITK>1: deterministic partials at C + z*(gridDim.y*128*ldc).
// OBF==1: output bf16 (u16) instead of fp32.
// ---------------------------------------------------------------------------
template<int ACT, int SPLITK, int TN, int OBF>
__global__ __launch_bounds__(256) void mgemm(
    const u16* __restrict__ A, int lda,
    const u16* __restrict__ Bt, int ldb,
    const float* __restrict__ bias,
    void* __restrict__ Cv, int ldc, int K)
{
  constexpr int WI = (TN == 128) ? 4 : 2;   // a-frags per wave
  __shared__ u16 Al[128 * 32];
  __shared__ u16 Bl[TN * 32];
  const int tid = threadIdx.x;
  const int bm = blockIdx.y * 128;
  const int bn = blockIdx.x * TN;
  const int lane = tid & 63;
  const int w = tid >> 6;
  const int wm = (TN == 128) ? (w & 1) * 64 : w * 32;
  const int wn = (TN == 128) ? (w >> 1) * 64 : 0;
  const int quad = lane >> 4;
  const int lm = lane & 15;

  const int Kper = K / SPLITK;
  const int k_beg = blockIdx.z * Kper;

  const int clog8 = (((lane & 3) ^ ((lane >> 3) & 3)) << 3);  // u16 offset
  const int rA = w * 32 + (lane >> 2);
  const int rB = ((TN == 128) ? w * 32 : w * 16) + (lane >> 2);
  const u16* gA0 = A + (size_t)(bm + rA) * lda + k_beg + clog8;
  const u16* gA1 = gA0 + (size_t)16 * lda;
  const u16* gB0 = Bt + (size_t)(bn + rB) * ldb + k_beg + clog8;
  const u16* gB1 = gB0 + (size_t)16 * ldb;
  u16* lA0 = &Al[(w * 32) * 32];
  u16* lA1 = &Al[(w * 32 + 16) * 32];
  u16* lB0 = &Bl[(((TN == 128) ? w * 32 : w * 16)) * 32];
  u16* lB1 = &Bl[((TN == 128) ? (w * 32 + 16) : 0) * 32];

  const int cph8 = ((quad ^ ((lm >> 1) & 3)) << 3);

  f32x4 acc[WI][4] = {};

  for (int ks = 0; ks < Kper; ks += 32) {
    gload_lds16(gA0, lA0);
    gload_lds16(gA1, lA1);
    gload_lds16(gB0, lB0);
    if (TN == 128) gload_lds16(gB1, lB1);
    gA0 += 32; gA1 += 32; gB0 += 32; gB1 += 32;
    __syncthreads();

    short8 a[WI], b[4];
#pragma unroll
    for (int i = 0; i < WI; ++i)
      a[i] = *(const short8*)&Al[(wm + i * 16 + lm) * 32 + cph8];
#pragma unroll
    for (int j = 0; j < 4; ++j)
      b[j] = *(const short8*)&Bl[(wn + j * 16 + lm) * 32 + cph8];
#pragma unroll
    for (int i = 0; i < WI; ++i)
#pragma unroll
      for (int j = 0; j < 4; ++j)
        acc[i][j] = __builtin_amdgcn_mfma_f32_16x16x32_bf16(a[i], b[j], acc[i][j], 0, 0, 0);
    __syncthreads();
  }

#pragma unroll
  for (int i = 0; i < WI; ++i) {
#pragma unroll
    for (int r = 0; r < 4; ++r) {
      const int row = bm + wm + i * 16 + quad * 4 + r;
#pragma unroll
      for (int j = 0; j < 4; ++j) {
        const int col = bn + wn + j * 16 + lm;
        float v = acc[i][j][r];
        if (ACT == 1) v = softplus_f(v + bias[col]);
        if (OBF) {
          ((u16*)Cv)[(size_t)row * ldc + col] = f2bf(v);
        } else {
          float* Cz = (float*)Cv;
          if (SPLITK > 1) Cz += (size_t)blockIdx.z * gridDim.y * 128 * ldc;
          Cz[(size_t)row * ldc + col] = v;
        }
      }
    }
  }
}

// ---------------------------------------------------------------------------
// Reduce gemm3's 8 split-K partials -> SSMB fp32, and emit bf16 dt slice.
// ---------------------------------------------------------------------------
__global__ __launch_bounds__(256) void reduce3_slice(
    const float* __restrict__ P3, float* __restrict__ SSMB,
    u16* __restrict__ SBdt)
{
  const int t = blockIdx.x * 256 + threadIdx.x;   // over 2048*128
  float s = 0.f;
#pragma unroll
  for (int z = 0; z < 8; ++z) s += P3[(size_t)z * (MROWS * SSMP) + t];
  SSMB[t] = s;
  const int n = t & (SSMP - 1), m = t >> 7;
  if (n < DTR) SBdt[m * DTR + n] = f2bf(s);
}

// ---------------------------------------------------------------------------
// Depthwise causal conv (k=4) + bias + SiLU. Reads XVb bf16, writes XSb bf16.
// ---------------------------------------------------------------------------
__global__ __launch_bounds__(256) void conv_silu_kernel(
    const u16* __restrict__ XVb, const float* __restrict__ cw,
    const float* __restrict__ cb, u16* __restrict__ XSb)
{
  const int idx = blockIdx.x * 256 + threadIdx.x;   // over B*L*DI
  const int d = idx & (DI - 1);
  const int bl = idx >> 11;
  const int l = bl & (LSEQ - 1);
  const float w0 = cw[d * 4 + 0], w1 = cw[d * 4 + 1];
  const float w2 = cw[d * 4 + 2], w3 = cw[d * 4 + 3];
  const u16* p = XVb + (size_t)idx;
  float acc = cb[d];
  acc = fmaf(w3, bf2f(p[0]), acc);
  if (l >= 1) acc = fmaf(w2, bf2f(p[-DI]), acc);
  if (l >= 2) acc = fmaf(w1, bf2f(p[-2 * DI]), acc);
  if (l >= 3) acc = fmaf(w0, bf2f(p[-3 * DI]), acc);
  XSb[idx] = f2bf(silu_f(acc));
}

// ---------------------------------------------------------------------------
// Chunked parallel scan, register-state version (one thread per (b,chunk,d)).
// ---------------------------------------------------------------------------
__global__ __launch_bounds__(256) void scan_pass1(
    const float* __restrict__ DELTA, const u16* __restrict__ XSb,
    const float* __restrict__ SSMB, const float* __restrict__ A_log,
    float* __restrict__ AGG_A, float* __restrict__ AGG_H)
{
  __shared__ float Bs[CHUNK * 16];
  const int tid = threadIdx.x;
  const int db = blockIdx.x & 7;
  const int c  = (blockIdx.x >> 3) & (NCHUNK - 1);
  const int b  = blockIdx.x >> 8;
  const int d  = db * 256 + tid;
  const int l0 = c * CHUNK;

  for (int i = tid; i < CHUNK * 16; i += 256) {
    const int l = i >> 4, n = i & 15;
    Bs[i] = SSMB[((size_t)(b * LSEQ + l0 + l)) * SSMP + DTR + n];
  }
  __syncthreads();

  float An[16];
  {
    const float* ar = A_log + d * 16;
#pragma unroll
    for (int n = 0; n < 16; ++n) An[n] = -__expf(ar[n]);
  }

  float h[16];
#pragma unroll
  for (int n = 0; n < 16; ++n) h[n] = 0.f;
  float S = 0.f;

  const float* dp = DELTA + ((size_t)(b * LSEQ + l0)) * DI + d;
  const u16*   xp = XSb   + ((size_t)(b * LSEQ + l0)) * DI + d;

  for (int l = 0; l < CHUNK; ++l) {
    const float delta = *dp; dp += DI;
    const float xv = bf2f(*xp); xp += DI;
    S += delta;
    const float dt = delta * xv;
    const f32x4 b0 = *(const f32x4*)&Bs[l * 16];
    const f32x4 b1 = *(const f32x4*)&Bs[l * 16 + 4];
    const f32x4 b2 = *(const f32x4*)&Bs[l * 16 + 8];
    const f32x4 b3 = *(const f32x4*)&Bs[l * 16 + 12];
#pragma unroll
    for (int n = 0; n < 16; ++n) {
      const float Bv = (n < 4) ? b0[n & 3] : (n < 8) ? b1[n & 3] : (n < 12) ? b2[n & 3] : b3[n & 3];
      const float dA = __expf(delta * An[n]);
      h[n] = fmaf(dA, h[n], Bv * dt);
    }
  }

  const size_t base = (((size_t)(b * NCHUNK + c) * DI + d) << 4);
  f32x4 oa[4], oh[4];
#pragma unroll
  for (int q = 0; q < 4; ++q) {
#pragma unroll
    for (int r = 0; r < 4; ++r) {
      oa[q][r] = __expf(An[q * 4 + r] * S);
      oh[q][r] = h[q * 4 + r];
    }
    *(f32x4*)&AGG_A[base + q * 4] = oa[q];
    *(f32x4*)&AGG_H[base + q * 4] = oh[q];
  }
}

// In-place prefix over chunks: AGG_H[ai] <- exclusive prefix (h_init).
__global__ __launch_bounds__(256) void scan_pass2(
    const float* __restrict__ AGG_A, float* __restrict__ AGG_H)
{
  const int t = blockIdx.x * 256 + threadIdx.x;   // over B*DI*NSTATE
  const int dn = t & (DI * NSTATE - 1);
  const int b = t >> 15;
  size_t ai = (size_t)b * NCHUNK * DI * NSTATE + dn;
  const size_t stride = (size_t)DI * NSTATE;
  float h = 0.f;
#pragma unroll
  for (int c = 0; c < NCHUNK; ++c) {
    const float a = AGG_A[ai];
    const float hp = AGG_H[ai];
    AGG_H[ai] = h;
    h = fmaf(a, h, hp);
    ai += stride;
  }
}

__global__ __launch_bounds__(256) void scan_pass3(
    const float* __restrict__ DELTA, const u16* __restrict__ XSb,
    const float* __restrict__ SSMB, const float* __restrict__ A_log,
    const float* __restrict__ Dp, const float* __restrict__ HINIT,
    u16* __restrict__ Yb)
{
  __shared__ float Bs[CHUNK * 16];
  __shared__ float Cs[CHUNK * 16];
  const int tid = threadIdx.x;
  const int db = blockIdx.x & 7;
  const int c  = (blockIdx.x >> 3) & (NCHUNK - 1);
  const int b  = blockIdx.x >> 8;
  const int d  = db * 256 + tid;
  const int l0 = c * CHUNK;

  for (int i = tid; i < CHUNK * 16; i += 256) {
    const int l = i >> 4, n = i & 15;
    const size_t row = ((size_t)(b * LSEQ + l0 + l)) * SSMP;
    Bs[i] = SSMB[row + DTR + n];
    Cs[i] = SSMB[row + DTR + NSTATE + n];
  }
  __syncthreads();

  float An[16];
  {
    const float* ar = A_log + d * 16;
#pragma unroll
    for (int n = 0; n < 16; ++n) An[n] = -__expf(ar[n]);
  }
  const float Dd = Dp[d];

  const size_t base = (((size_t)(b * NCHUNK + c) * DI + d) << 4);
  float h[16];
#pragma unroll
  for (int q = 0; q < 4; ++q) {
    const f32x4 hv = *(const f32x4*)&HINIT[base + q * 4];
#pragma unroll
    for (int r = 0; r < 4; ++r) h[q * 4 + r] = hv[r];
  }

  const float* dp = DELTA + ((size_t)(b * LSEQ + l0)) * DI + d;
  const u16*   xp = XSb   + ((size_t)(b * LSEQ + l0)) * DI + d;
  u16*         yp = Yb    + ((size_t)(b * LSEQ + l0)) * DI + d;

  for (int l = 0; l < CHUNK; ++l) {
    const float delta = *dp; dp += DI;
    const float xv = bf2f(*xp); xp += DI;
    const float dt = delta * xv;
    float y = xv * Dd;
    const f32x4 b0 = *(const f32x4*)&Bs[l * 16];
    const f32x4 b1 = *(const f32x4*)&Bs[l * 16 + 4];
    const f32x4 b2 = *(const f32x4*)&Bs[l * 16 + 8];
    const f32x4 b3 = *(const f32x4*)&Bs[l * 16 + 12];
    const f32x4 c0 = *(const f32x4*)&Cs[l * 16];
    const f32x4 c1 = *(const f32x4*)&Cs[l * 16 + 4];
    const f32x4 c2 = *(const f32x4*)&Cs[l * 16 + 8];
    const f32x4 c3 = *(const f32x4*)&Cs[l * 16 + 12];
#pragma unroll
    for (int n = 0; n < 16; ++n) {
      const float Bv = (n < 4) ? b0[n & 3] : (n < 8) ? b1[n & 3] : (n < 12) ? b2[n & 3] : b3[n & 3];
      const float Cv = (n < 4) ? c0[n & 3] : (n < 8) ? c1[n & 3] : (n < 12) ? c2[n & 3] : c3[n & 3];
      const float dA = __expf(delta * An[n]);
      h[n] = fmaf(dA, h[n], Bv * dt);
      y = fmaf(h[n], Cv, y);
    }
    *yp = f2bf(y); yp += DI;
  }
}

// ---------------------------------------------------------------------------
extern "C" void kernel_launch(void* const* d_in, const int* in_sizes, int n_in,
                              void* d_out, int out_size, void* d_ws, size_t ws_size,
                              hipStream_t stream)
{
  const float* x      = (const float*)d_in[0];
  const float* W_in   = (const float*)d_in[1];
  const float* conv_w = (const float*)d_in[2];
  const float* conv_b = (const float*)d_in[3];
  const float* W_x    = (const float*)d_in[4];
  const float* W_dt   = (const float*)d_in[5];
  const float* b_dt   = (const float*)d_in[6];
  const float* A_log  = (const float*)d_in[7];
  const float* Dp     = (const float*)d_in[8];
  const float* W_out  = (const float*)d_in[9];
  float* out = (float*)d_out;
  char* W = (char*)d_ws;

  const size_t MB = 1u << 20;
  // byte layout (46 MB), time-multiplexed:
  // [0,8)   : XVb bf16 (gemm1->conv) -> AGG_A (scan1->2) -> Yb (scan3->gemm6)
  // [8,16)  : AGG_H (scan1->3, in-place HINIT after pass2)
  // [16,32) : x_bf[16,20)+WinT[20,24) (prep->gemm1) -> P3 8MB [16,24)
  //           (gemm3->reduce3) -> DELTA 16MB [16,32) (gemm4->scan)
  // [32,40) : XSb bf16
  // [40,41) : SSMB fp32 [2048][128]
  // [41,45) : WoutT
  // [45,46) : WxT[45,45.5) + WdtT[45.5,45.75) + SBdt[45.75,46)
  u16*   XVb   = (u16*)  (W + 0);
  float* AGG_A = (float*)(W + 0);
  u16*   Yb    = (u16*)  (W + 0);
  float* AGG_H = (float*)(W + 8 * MB);
  u16*   x_bf  = (u16*)  (W + 16 * MB);
  u16*   WinT  = (u16*)  (W + 20 * MB);
  float* P3    = (float*)(W + 16 * MB);
  float* DELTA = (float*)(W + 16 * MB);
  u16*   XSb   = (u16*)  (W + 32 * MB);
  float* SSMB  = (float*)(W + 40 * MB);
  u16*   WoutT = (u16*)  (W + 41 * MB);
  u16*   WxT   = (u16*)  (W + 45 * MB);
  u16*   WdtT  = (u16*)  (W + 45 * MB + 512 * 1024);
  u16*   SBdt  = (u16*)  (W + 45 * MB + 768 * 1024);

  dim3 blk(256);

  // 0) fused preprocessing (cvt + 4 transposes + WxT pad-zero)
  prep_kernel<<<dim3(6528), blk, 0, stream>>>(
      x, W_in, W_x, W_dt, W_out, x_bf, WinT, WxT, WdtT, WoutT);

  // 1) xv = x @ W_in  (M=2048 N=2048 K=1024), TN=64, bf16 out -> XVb
  mgemm<0, 1, 64, 1><<<dim3(32, 16, 1), blk, 0, stream>>>(
      x_bf, DMODEL, WinT, DMODEL, nullptr, XVb, DI, DMODEL);

  // 2) conv + silu (bf16 in) -> XSb bf16
  conv_silu_kernel<<<dim3((BATCH * LSEQ * DI) / 256), blk, 0, stream>>>(
      XVb, conv_w, conv_b, XSb);

  // 3) ssm partials (M=2048 N=128pad K=2048, TN=64 splitK=8) -> P3, reduce
  mgemm<0, 8, 64, 0><<<dim3(2, 16, 8), blk, 0, stream>>>(
      XSb, DI, WxT, DI, nullptr, P3, SSMP, DI);
  reduce3_slice<<<dim3(MROWS * SSMP / 256), blk, 0, stream>>>(P3, SSMB, SBdt);

  // 4) delta = softplus(ssm[:, :64] @ W_dt + b_dt)  (K=64, TN=64) -> DELTA
  mgemm<1, 1, 64, 0><<<dim3(32, 16, 1), blk, 0, stream>>>(
      SBdt, DTR, WdtT, DTR, b_dt, DELTA, DI, DTR);

  // 5) chunked scan (register-state)
  scan_pass1<<<dim3(BATCH * NCHUNK * (DI / 256)), blk, 0, stream>>>(
      DELTA, XSb, SSMB, A_log, AGG_A, AGG_H);
  scan_pass2<<<dim3((BATCH * DI * NSTATE) / 256), blk, 0, stream>>>(
      AGG_A, AGG_H);
  scan_pass3<<<dim3(BATCH * NCHUNK * (DI / 256)), blk, 0, stream>>>(
      DELTA, XSb, SSMB, A_log, Dp, AGG_H, Yb);

  // 6) out = y @ W_out  (M=2048 N=1024 K=2048, TN=64, splitK=1) -> d_out
  mgemm<0, 1, 64, 0><<<dim3(16, 16, 1), blk, 0, stream>>>(
      Yb, DI, WoutT, DI, nullptr, out, DMODEL, DI);
}